// Round 11
// baseline (342.285 us; speedup 1.0000x reference)
//
#include <hip/hip_runtime.h>
#include <hip/hip_bf16.h>
#include <math.h>

typedef unsigned short u16;
typedef unsigned int u32;
typedef __attribute__((ext_vector_type(8))) short bf16x8;
typedef __attribute__((ext_vector_type(4))) float f32x4;
typedef __attribute__((ext_vector_type(2))) unsigned int u32x2;
typedef __attribute__((ext_vector_type(4))) unsigned int u32x4;

#define B_ 8
#define M_ 1024
#define DM_ 1024
#define H_ 16
#define DH_ 64
#define NR_ 8192

__device__ __forceinline__ u16 f2bf(float f) {
    unsigned u = __float_as_uint(f);
    u += 0x7FFFu + ((u >> 16) & 1u);
    return (u16)(u >> 16);
}

__device__ __forceinline__ float bf2f(u16 v) {
    return __uint_as_float((u32)v << 16);
}

__device__ __forceinline__ void gload16(const void* g, void* l) {
    __builtin_amdgcn_global_load_lds(
        (const __attribute__((address_space(1))) void*)g,
        (__attribute__((address_space(3))) void*)l, 16, 0, 0);
}

__device__ __forceinline__ u32 lds_addr(const void* p) {
    return (u32)(uintptr_t)(const __attribute__((address_space(3))) void*)p;
}

// fast exact-enough gelu: Abramowitz-Stegun 7.1.26 erf (|eps| < 1.5e-7)
__device__ __forceinline__ float gelu_f(float x) {
    float ax = fabsf(x);
    float t = 1.f / fmaf(0.3275911f, ax, 1.f);
    float poly = t * fmaf(t, fmaf(t, fmaf(t, fmaf(t, 1.061405429f, -1.453152027f),
                                          1.421413741f), -0.284496736f), 0.254829592f);
    float er = 1.f - poly * __expf(-ax * ax);
    er = copysignf(er, x);
    return 0.5f * x * (1.f + er);
}

// ---------------------------------------------------------------------------
// Mega-prep: x->bf16, P transposes, V-factor transposes, 6 weight transposes.
// ---------------------------------------------------------------------------
__device__ void conv_dev(const float* __restrict__ in, u16* __restrict__ out,
                         int bid, int tid) {
#pragma unroll
    for (int j = 0; j < 4; ++j) {
        int i = bid * 4096 + j * 1024 + tid * 4;
        float4 v = *reinterpret_cast<const float4*>(in + i);
        unsigned long long p = (unsigned long long)f2bf(v.x)
                             | ((unsigned long long)f2bf(v.y) << 16)
                             | ((unsigned long long)f2bf(v.z) << 32)
                             | ((unsigned long long)f2bf(v.w) << 48);
        *reinterpret_cast<unsigned long long*>(out + i) = p;
    }
}

__device__ void prep_p_dev(const float* __restrict__ P, u16* __restrict__ Pt,
                           int h, int kc, int tid, float* sm) {
    float (*Ps)[33] = (float(*)[33])sm;
#pragma unroll
    for (int i = 0; i < 16; ++i) {
        int e = tid + i * 256;
        int kk = e >> 5, r = e & 31;
        Ps[kk][r] = P[(size_t)h * 32768 + (size_t)(kc + kk) * 32 + r];
    }
    __syncthreads();
#pragma unroll
    for (int i = 0; i < 16; ++i) {
        int e = tid + i * 256;
        int r = e >> 7, k = e & 127;
        Pt[(size_t)(h * 32 + r) * 1024 + kc + k] = f2bf(Ps[k][r]);
    }
}

__device__ void prep_f_dev(const float* __restrict__ V, u16* __restrict__ Ft,
                           int h, int tid, float* sm) {
    float (*Vs)[65] = (float(*)[65])sm;
#pragma unroll
    for (int i = 0; i < 8; ++i) {
        int e = tid + i * 256;
        int r = e >> 6, c = e & 63;
        Vs[r][c] = V[(size_t)h * 2048 + r * 64 + c];
    }
    __syncthreads();
#pragma unroll
    for (int i = 0; i < 8; ++i) {
        int idx = tid + i * 256;
        int e = idx >> 5, r = idx & 31;
        Ft[(size_t)h * 2560 + e * 40 + r] = f2bf(Vs[r][e]);
    }
}

__device__ void transp_dev(const float* __restrict__ in, u16* __restrict__ out,
                           int R, int C, int bx, int by, int tid, float* sm) {
    float (*t)[65] = (float(*)[65])sm;
    const int rb = by * 64, cb = bx * 64;
#pragma unroll
    for (int i = 0; i < 16; ++i) {
        int e = tid + i * 256;
        int r = e >> 6, c = e & 63;
        t[r][c] = in[(size_t)(rb + r) * C + cb + c];
    }
    __syncthreads();
#pragma unroll
    for (int i = 0; i < 16; ++i) {
        int e = tid + i * 256;
        int r = e >> 6, c = e & 63;
        out[(size_t)(cb + r) * R + rb + c] = f2bf(t[c][r]);
    }
}

__global__ __launch_bounds__(256) void prep_all(
    const float* __restrict__ x,
    const float* __restrict__ Pq, const float* __restrict__ Pk, const float* __restrict__ Pv,
    const float* __restrict__ Vq, const float* __restrict__ Vk, const float* __restrict__ Vv,
    const float* __restrict__ Uo, const float* __restrict__ Vo,
    const float* __restrict__ U1, const float* __restrict__ V1,
    const float* __restrict__ U2, const float* __restrict__ V2,
    u16* __restrict__ Xb, u16* __restrict__ Pt,
    u16* __restrict__ Ftq, u16* __restrict__ Ftk, u16* __restrict__ Ftv,
    u16* __restrict__ Uot, u16* __restrict__ Vot,
    u16* __restrict__ U1t, u16* __restrict__ V1t,
    u16* __restrict__ U2t, u16* __restrict__ V2t) {
    __shared__ float smem[4224];
    const int bid = blockIdx.x, tid = threadIdx.x;
    if (bid < 2048) {
        conv_dev(x, Xb, bid, tid);
    } else if (bid < 2432) {
        int t = bid - 2048, which = t >> 7, tt = t & 127;
        const float* P = which == 0 ? Pq : (which == 1 ? Pk : Pv);
        prep_p_dev(P, Pt + (size_t)which * 524288, tt >> 3, (tt & 7) * 128, tid, smem);
    } else if (bid < 2480) {
        int t = bid - 2432, which = t >> 4;
        const float* V = which == 0 ? Vq : (which == 1 ? Vk : Vv);
        u16* F = which == 0 ? Ftq : (which == 1 ? Ftk : Ftv);
        prep_f_dev(V, F, t & 15, tid, smem);
    } else if (bid < 2608) {
        int t = bid - 2480;
        transp_dev(Uo, Uot, 1024, 512, t & 7, t >> 3, tid, smem);
    } else if (bid < 2736) {
        int t = bid - 2608;
        transp_dev(Vo, Vot, 512, 1024, t & 15, t >> 4, tid, smem);
    } else if (bid < 2864) {
        int t = bid - 2736;
        transp_dev(U1, U1t, 1024, 512, t & 7, t >> 3, tid, smem);
    } else if (bid < 3376) {
        int t = bid - 2864;
        transp_dev(V1, V1t, 512, 4096, t & 63, t >> 6, tid, smem);
    } else if (bid < 3888) {
        int t = bid - 3376;
        transp_dev(U2, U2t, 4096, 512, t & 7, t >> 3, tid, smem);
    } else {
        int t = bid - 3888;
        transp_dev(V2, V2t, 512, 1024, t & 15, t >> 4, tid, smem);
    }
}

// ---------------------------------------------------------------------------
// bf16 MFMA GEMM (single-buffer): C(8192 x N) = A(8192 x K) @ Bt(N x K)^T
// EPI: 0 bf16, 2 bias+gelu bf16.
// ---------------------------------------------------------------------------
template <int EPI, int NF>
__global__ __launch_bounds__(256) void gemm_bf16(const u16* __restrict__ A,
                                                 const u16* __restrict__ Bt,
                                                 const float* __restrict__ bias,
                                                 void* __restrict__ Cout,
                                                 int K, int N) {
    constexpr int BN = NF * 32;
    __shared__ u16 As[128 * 64];
    __shared__ u16 Bs[BN * 64];
    const int tid = threadIdx.x;
    const int lane = tid & 63, wv = tid >> 6;

    const int NX = gridDim.x;
    const int flat = blockIdx.x + blockIdx.y * NX;
    const int q = (NX * gridDim.y) >> 3;
    const int nid = (flat & 7) * q + (flat >> 3);
    const int row0 = (nid / NX) * 128, col0 = (nid % NX) * BN;

    const int frow = lane & 15, fk8 = lane >> 4;
    const int wm = (wv >> 1) * 64, wn = (wv & 1) * (BN / 2);

    f32x4 acc[4][NF];
    const f32x4 z4 = {0.f, 0.f, 0.f, 0.f};
#pragma unroll
    for (int i = 0; i < 4; ++i)
#pragma unroll
        for (int j = 0; j < NF; ++j) acc[i][j] = z4;

    for (int k0 = 0; k0 < K; k0 += 64) {
#pragma unroll
        for (int i = 0; i < 4; ++i) {
            int rr = (i * 4 + wv) * 8 + (lane >> 3);
            int cc = ((lane & 7) ^ (rr & 7)) * 8;
            gload16(A + (size_t)(row0 + rr) * K + k0 + cc,
                    (char*)As + (i * 4 + wv) * 1024);
        }
#pragma unroll
        for (int i = 0; i < NF; ++i) {
            int rr = (i * 4 + wv) * 8 + (lane >> 3);
            int cc = ((lane & 7) ^ (rr & 7)) * 8;
            gload16(Bt + (size_t)(col0 + rr) * K + k0 + cc,
                    (char*)Bs + (i * 4 + wv) * 1024);
        }
        asm volatile("s_waitcnt vmcnt(0)" ::: "memory");
        __syncthreads();
#pragma unroll
        for (int kf = 0; kf < 2; ++kf) {
            bf16x8 af[4], bfr[NF];
#pragma unroll
            for (int mf = 0; mf < 4; ++mf) {
                int r = wm + mf * 16 + frow;
                int c16 = (kf * 4 + fk8) ^ (r & 7);
                af[mf] = *reinterpret_cast<const bf16x8*>((char*)As + r * 128 + c16 * 16);
            }
#pragma unroll
            for (int nf = 0; nf < NF; ++nf) {
                int r = wn + nf * 16 + frow;
                int c16 = (kf * 4 + fk8) ^ (r & 7);
                bfr[nf] = *reinterpret_cast<const bf16x8*>((char*)Bs + r * 128 + c16 * 16);
            }
#pragma unroll
            for (int mf = 0; mf < 4; ++mf)
#pragma unroll
                for (int nf = 0; nf < NF; ++nf)
                    acc[mf][nf] = __builtin_amdgcn_mfma_f32_16x16x32_bf16(
                        af[mf], bfr[nf], acc[mf][nf], 0, 0, 0);
        }
        __syncthreads();
    }

    const int orow = fk8 * 4, ocol = frow;
#pragma unroll
    for (int mf = 0; mf < 4; ++mf)
#pragma unroll
        for (int nf = 0; nf < NF; ++nf)
#pragma unroll
            for (int j = 0; j < 4; ++j) {
                int row = row0 + wm + mf * 16 + orow + j;
                int col = col0 + wn + nf * 16 + ocol;
                float v = acc[mf][nf][j];
                if (EPI == 2) {
                    v += bias[col];
                    v = gelu_f(v);
                    ((u16*)Cout)[(size_t)row * N + col] = f2bf(v);
                } else {
                    ((u16*)Cout)[(size_t)row * N + col] = f2bf(v);
                }
            }
}

// ---------------------------------------------------------------------------
// 8-phase 256x256 GEMM (catalog T3+T4) specialized for mid@V1:
// C(8192x4096) = gelu(A(8192x512) @ V1t(4096x512)^T + b1), bf16 out.
// 512 thr = 8 waves (2M x 4N, 128x64 C each).  LDS 128 KB = 2 slots x
// {A-lo,A-hi,B-lo,B-hi} 16KB half-tiles.  Per K-tile: 4 phases of
// {ds_read frags | stage 1 half-tile -> barrier -> 16 MFMA -> barrier}.
// B-frags hoisted to regs at phase 0 (B LDS dead after p0 -> B(kt+2)
// restages into the CURRENT slot at p2/p3; A(kt+1) into the other slot at
// p0/p1).  Counted vmcnt(4) once per K-tile boundary; never 0 until tail.
// ---------------------------------------------------------------------------
__device__ __forceinline__ void stage_half_512(const u16* __restrict__ ptr, int grow,
                                               int k0, u16* S, int dstbase,
                                               int tid, int wv) {
#pragma unroll
    for (int i = 0; i < 2; ++i) {
        int idx2 = i * 512 + tid;
        int r = idx2 >> 3, seg = idx2 & 7;
        int cc = (seg ^ (r & 7)) * 8;
        gload16(ptr + (size_t)(grow + r) * 512 + k0 + cc,
                (char*)S + dstbase + i * 8192 + wv * 1024);
    }
}

__global__ __launch_bounds__(512, 2) void gemm_8ph(const u16* __restrict__ A,
                                                   const u16* __restrict__ Bt,
                                                   const float* __restrict__ bias,
                                                   u16* __restrict__ C) {
    __shared__ u16 S[65536];   // 128 KB
    const int tid = threadIdx.x, lane = tid & 63, wv = tid >> 6;
    const int frow = lane & 15, fk8 = lane >> 4;
    const int wm2 = wv >> 2, wn4 = wv & 3;

    // XCD-chunked remap over grid (16, 32) = 512 blocks
    const int flat = blockIdx.x + blockIdx.y * 16;
    const int nid = (flat & 7) * 64 + (flat >> 3);
    const int row0 = (nid >> 4) * 256, col0 = (nid & 15) * 256;

    f32x4 acc[8][4];
    const f32x4 z4 = {0.f, 0.f, 0.f, 0.f};
#pragma unroll
    for (int i = 0; i < 8; ++i)
#pragma unroll
        for (int j = 0; j < 4; ++j) acc[i][j] = z4;

    // prologue: A(0), B(0), B(1); confirm A(0)+B(0); leave B(1) in flight
    stage_half_512(A, row0, 0, S, 0, tid, wv);
    stage_half_512(A, row0 + 128, 0, S, 16384, tid, wv);
    stage_half_512(Bt, col0, 0, S, 32768, tid, wv);
    stage_half_512(Bt, col0 + 128, 0, S, 49152, tid, wv);
    stage_half_512(Bt, col0, 64, S, 65536 + 32768, tid, wv);
    stage_half_512(Bt, col0 + 128, 64, S, 65536 + 49152, tid, wv);
    asm volatile("s_waitcnt vmcnt(4)" ::: "memory");
    __syncthreads();

    for (int kt = 0; kt < 8; ++kt) {
        const int sb = (kt & 1) * 32768 * 2;   // slot base (bytes = *2 for u16)
        const int so = sb ^ 65536;
        const int abase = sb + wm2 * 16384;
        const int bbase = sb + 32768 + (wn4 >> 1) * 16384;
        bf16x8 bfr[4][2];
#pragma unroll
        for (int p = 0; p < 4; ++p) {
            if (p == 0) {
#pragma unroll
                for (int nf = 0; nf < 4; ++nf)
#pragma unroll
                    for (int kf = 0; kf < 2; ++kf) {
                        int r = (wn4 & 1) * 64 + nf * 16 + frow;
                        bfr[nf][kf] = *reinterpret_cast<const bf16x8*>(
                            (char*)S + bbase + r * 128 + (((kf * 4 + fk8) ^ (r & 7)) * 16));
                    }
            }
            bf16x8 af[2][2];
#pragma unroll
            for (int i = 0; i < 2; ++i)
#pragma unroll
                for (int kf = 0; kf < 2; ++kf) {
                    int r = (2 * p + i) * 16 + frow;
                    af[i][kf] = *reinterpret_cast<const bf16x8*>(
                        (char*)S + abase + r * 128 + (((kf * 4 + fk8) ^ (r & 7)) * 16));
                }
            // stage exactly one half-tile this phase
            if (p == 0 && kt + 1 < 8)
                stage_half_512(A, row0, (kt + 1) * 64, S, so + 0, tid, wv);
            if (p == 1 && kt + 1 < 8)
                stage_half_512(A, row0 + 128, (kt + 1) * 64, S, so + 16384, tid, wv);
            if (p == 2 && kt + 2 < 8)
                stage_half_512(Bt, col0, (kt + 2) * 64, S, sb + 32768, tid, wv);
            if (p == 3 && kt + 2 < 8)
                stage_half_512(Bt, col0 + 128, (kt + 2) * 64, S, sb + 49152, tid, wv);
            __syncthreads();
            __builtin_amdgcn_s_setprio(1);
#pragma unroll
            for (int i = 0; i < 2; ++i)
#pragma unroll
                for (int nf = 0; nf < 4; ++nf)
#pragma unroll
                    for (int kf = 0; kf < 2; ++kf)
                        acc[2 * p + i][nf] = __builtin_amdgcn_mfma_f32_16x16x32_bf16(
                            af[i][kf], bfr[nf][kf], acc[2 * p + i][nf], 0, 0, 0);
            __builtin_amdgcn_s_setprio(0);
            if (p == 3 && kt < 7) {
                if (kt < 6)
                    asm volatile("s_waitcnt vmcnt(4)" ::: "memory");
                else
                    asm volatile("s_waitcnt vmcnt(0)" ::: "memory");
            }
            __syncthreads();
        }
    }

    // epilogue: bias + gelu + bf16 store
#pragma unroll
    for (int mf = 0; mf < 8; ++mf)
#pragma unroll
        for (int nf = 0; nf < 4; ++nf) {
            int col = col0 + wn4 * 64 + nf * 16 + frow;
            float bv = bias[col];
#pragma unroll
            for (int j = 0; j < 4; ++j) {
                int row = row0 + wm2 * 128 + mf * 16 + fk8 * 4 + j;
                float v = gelu_f(acc[mf][nf][j] + bv);
                C[(size_t)row * 4096 + col] = f2bf(v);
            }
        }
}

// ---------------------------------------------------------------------------
// QKV fused GEMM: stage-1 matmul kept in regs, per-head rank-32 transform in
// the epilogue via wave-local LDS transpose, direct Q/K/V (+bias) scatter.
// ---------------------------------------------------------------------------
__global__ __launch_bounds__(256) void gemm_qkv(const u16* __restrict__ A,
                                                const u16* __restrict__ Bt,
                                                const u16* __restrict__ Ftq,
                                                const u16* __restrict__ Ftk,
                                                const u16* __restrict__ Ftv,
                                                const float* __restrict__ bq,
                                                const float* __restrict__ bk,
                                                const float* __restrict__ bv,
                                                u16* __restrict__ Qo,
                                                u16* __restrict__ Ko,
                                                u16* __restrict__ Vo) {
    const int K = 1024;
    __shared__ u16 As[128 * 64];
    __shared__ u16 Bs[128 * 64];
    const int tid = threadIdx.x;
    const int lane = tid & 63, wv = tid >> 6;

    const int NX = gridDim.x;
    const int flat = blockIdx.x + blockIdx.y * NX;
    const int q = (NX * gridDim.y) >> 3;
    const int nid = (flat & 7) * q + (flat >> 3);
    const int row0 = (nid / NX) * 128, col0 = (nid % NX) * 128;

    const int frow = lane & 15, fk8 = lane >> 4;
    const int wm = (wv >> 1) * 64, wn = (wv & 1) * 64;

    f32x4 acc[4][4];
    const f32x4 z4 = {0.f, 0.f, 0.f, 0.f};
#pragma unroll
    for (int i = 0; i < 4; ++i)
#pragma unroll
        for (int j = 0; j < 4; ++j) acc[i][j] = z4;

    for (int k0 = 0; k0 < K; k0 += 64) {
#pragma unroll
        for (int i = 0; i < 4; ++i) {
            int rr = (i * 4 + wv) * 8 + (lane >> 3);
            int cc = ((lane & 7) ^ (rr & 7)) * 8;
            gload16(A + (size_t)(row0 + rr) * K + k0 + cc,
                    (char*)As + (i * 4 + wv) * 1024);
            gload16(Bt + (size_t)(col0 + rr) * K + k0 + cc,
                    (char*)Bs + (i * 4 + wv) * 1024);
        }
        asm volatile("s_waitcnt vmcnt(0)" ::: "memory");
        __syncthreads();
#pragma unroll
        for (int kf = 0; kf < 2; ++kf) {
            bf16x8 af[4], bfr[4];
#pragma unroll
            for (int mf = 0; mf < 4; ++mf) {
                int r = wm + mf * 16 + frow;
                int c16 = (kf * 4 + fk8) ^ (r & 7);
                af[mf] = *reinterpret_cast<const bf16x8*>((char*)As + r * 128 + c16 * 16);
            }
#pragma unroll
            for (int nf = 0; nf < 4; ++nf) {
                int r = wn + nf * 16 + frow;
                int c16 = (kf * 4 + fk8) ^ (r & 7);
                bfr[nf] = *reinterpret_cast<const bf16x8*>((char*)Bs + r * 128 + c16 * 16);
            }
#pragma unroll
            for (int mf = 0; mf < 4; ++mf)
#pragma unroll
                for (int nf = 0; nf < 4; ++nf)
                    acc[mf][nf] = __builtin_amdgcn_mfma_f32_16x16x32_bf16(
                        af[mf], bfr[nf], acc[mf][nf], 0, 0, 0);
        }
        __syncthreads();
    }

    // --- epilogue: per-head rank-32 transform -------------------------------
    u16* preg = (wv < 2) ? As + wv * 4096 : Bs + (wv - 2) * 4096;
#pragma unroll
    for (int mf = 0; mf < 4; ++mf)
#pragma unroll
        for (int nf = 0; nf < 4; ++nf)
#pragma unroll
            for (int j = 0; j < 4; ++j) {
                int r = mf * 16 + fk8 * 4 + j;
                int c = nf * 16 + frow;
                int byte = r * 128 + (((c >> 3) ^ (r & 7)) * 16) + (c & 7) * 2;
                *(u16*)((char*)preg + byte) = f2bf(acc[mf][nf][j]);
            }
    __syncthreads();

    const int f = col0 >> 9;                       // 0=q, 1=k, 2=v
    const u16* Ft = f == 0 ? Ftq : (f == 1 ? Ftk : Ftv);
    const float* bias = f == 0 ? bq : (f == 1 ? bk : bv);
    u16* outp = f == 0 ? Qo : (f == 1 ? Ko : Vo);
    const int h0 = (((col0 & 511) + wn) >> 5);

#pragma unroll
    for (int hh = 0; hh < 2; ++hh) {
        const int h = h0 + hh;
        const u16* ftb = Ft + (size_t)h * 2560;
        bf16x8 bf2[4];
#pragma unroll
        for (int ef = 0; ef < 4; ++ef) {
            int e = ef * 16 + frow;
            bf2[ef] = *reinterpret_cast<const bf16x8*>(ftb + e * 40 + fk8 * 8);
        }
#pragma unroll
        for (int mf = 0; mf < 4; ++mf) {
            int r = mf * 16 + frow;
            bf16x8 af = *reinterpret_cast<const bf16x8*>(
                (char*)preg + r * 128 + (((hh * 4 + fk8) ^ (r & 7)) * 16));
#pragma unroll
            for (int ef = 0; ef < 4; ++ef) {
                f32x4 o = __builtin_amdgcn_mfma_f32_16x16x32_bf16(af, bf2[ef], z4, 0, 0, 0);
                int e = ef * 16 + frow;
                float bv_ = bias[h * 64 + e];
#pragma unroll
                for (int j = 0; j < 4; ++j) {
                    int row = row0 + wm + mf * 16 + fk8 * 4 + j;
                    int bb = row >> 10, m = row & 1023;
                    outp[(((size_t)(bb * 16 + h) << 10) + m) * 64 + e] = f2bf(o[j] + bv_);
                }
            }
        }
    }
}

// ---------------------------------------------------------------------------
// Double-buffered prefetch GEMM for N=512 outputs (BN=64, bf16 out).
// ---------------------------------------------------------------------------
__global__ __launch_bounds__(256) void gemm_db(const u16* __restrict__ A,
                                               const u16* __restrict__ Bt,
                                               u16* __restrict__ Cout,
                                               int K, int N) {
    __shared__ u16 As[2][128 * 64];
    __shared__ u16 Bs[2][64 * 64];
    const int tid = threadIdx.x;
    const int lane = tid & 63, wv = tid >> 6;

    const int NX = gridDim.x;
    const int flat = blockIdx.x + blockIdx.y * NX;
    const int q = (NX * gridDim.y) >> 3;
    const int nid = (flat & 7) * q + (flat >> 3);
    const int row0 = (nid / NX) * 128, col0 = (nid % NX) * 64;

    const int frow = lane & 15, fk8 = lane >> 4;
    const int wm = (wv >> 1) * 64, wn = (wv & 1) * 32;

    f32x4 acc[4][2];
    const f32x4 z4 = {0.f, 0.f, 0.f, 0.f};
#pragma unroll
    for (int i = 0; i < 4; ++i) {
        acc[i][0] = z4;
        acc[i][1] = z4;
    }

    const int srr = (lane >> 3);
    const int scc = (lane & 7);

#pragma unroll
    for (int i = 0; i < 4; ++i) {
        int rr = (i * 4 + wv) * 8 + srr;
        int cc = (scc ^ (rr & 7)) * 8;
        gload16(A + (size_t)(row0 + rr) * K + cc, (char*)&As[0][0] + (i * 4 + wv) * 1024);
    }
#pragma unroll
    for (int i = 0; i < 2; ++i) {
        int rr = (i * 4 + wv) * 8 + srr;
        int cc = (scc ^ (rr & 7)) * 8;
        gload16(Bt + (size_t)(col0 + rr) * K + cc, (char*)&Bs[0][0] + (i * 4 + wv) * 1024);
    }

    int cur = 0;
    for (int k0 = 0; k0 < K; k0 += 64) {
        __syncthreads();
        if (k0 + 64 < K) {
            int kn = k0 + 64;
#pragma unroll
            for (int i = 0; i < 4; ++i) {
                int rr = (i * 4 + wv) * 8 + srr;
                int cc = (scc ^ (rr & 7)) * 8;
                gload16(A + (size_t)(row0 + rr) * K + kn + cc,
                        (char*)&As[cur ^ 1][0] + (i * 4 + wv) * 1024);
            }
#pragma unroll
            for (int i = 0; i < 2; ++i) {
                int rr = (i * 4 + wv) * 8 + srr;
                int cc = (scc ^ (rr & 7)) * 8;
                gload16(Bt + (size_t)(col0 + rr) * K + kn + cc,
                        (char*)&Bs[cur ^ 1][0] + (i * 4 + wv) * 1024);
            }
        }
#pragma unroll
        for (int kf = 0; kf < 2; ++kf) {
            bf16x8 af[4], bfr[2];
#pragma unroll
            for (int mf = 0; mf < 4; ++mf) {
                int r = wm + mf * 16 + frow;
                int c16 = (kf * 4 + fk8) ^ (r & 7);
                af[mf] = *reinterpret_cast<const bf16x8*>((char*)&As[cur][0] + r * 128 + c16 * 16);
            }
#pragma unroll
            for (int nf = 0; nf < 2; ++nf) {
                int r = wn + nf * 16 + frow;
                int c16 = (kf * 4 + fk8) ^ (r & 7);
                bfr[nf] = *reinterpret_cast<const bf16x8*>((char*)&Bs[cur][0] + r * 128 + c16 * 16);
            }
#pragma unroll
            for (int mf = 0; mf < 4; ++mf)
#pragma unroll
                for (int nf = 0; nf < 2; ++nf)
                    acc[mf][nf] = __builtin_amdgcn_mfma_f32_16x16x32_bf16(
                        af[mf], bfr[nf], acc[mf][nf], 0, 0, 0);
        }
        cur ^= 1;
    }

#pragma unroll
    for (int mf = 0; mf < 4; ++mf)
#pragma unroll
        for (int nf = 0; nf < 2; ++nf)
#pragma unroll
            for (int j = 0; j < 4; ++j) {
                int row = row0 + wm + mf * 16 + fk8 * 4 + j;
                int col = col0 + wn + nf * 16 + frow;
                Cout[(size_t)row * N + col] = f2bf(acc[mf][nf][j]);
            }
}

// ---------------------------------------------------------------------------
// MFMA flash attention — round-5 variant (best measured: 92 us).
// ---------------------------------------------------------------------------
__global__ __launch_bounds__(256) void attn_mfma(const u16* __restrict__ Q,
                                                 const u16* __restrict__ K,
                                                 const u16* __restrict__ V,
                                                 const float* __restrict__ mask,
                                                 u16* __restrict__ O) {
    __shared__ u16 Ks[4096];
    __shared__ u16 Vt[4096];
    __shared__ u16 Pw[4096];
    const int flat = blockIdx.x;
    const int nid = (flat & 7) * 256 + (flat >> 3);
    const int hb = nid >> 4, qt = nid & 15;
    const int b = hb >> 4, h = hb & 15;
    const int tid = threadIdx.x, lane = tid & 63, wv = tid >> 6;
    const int frow = lane & 15, fk8 = lane >> 4;
    const size_t base = (size_t)hb * 65536;
    const float LOG2E = 1.44269504089f;
    const int srr = lane >> 3, scc = lane & 7;

#pragma unroll
    for (int i = 0; i < 2; ++i) {
        int rr = (i * 4 + wv) * 8 + srr;
        int cc = (scc ^ (rr & 7)) * 8;
        gload16(Q + base + (size_t)(qt * 64 + rr) * 64 + cc,
                (char*)Ks + (i * 4 + wv) * 1024);
    }
    asm volatile("s_waitcnt vmcnt(0)" ::: "memory");
    __syncthreads();
    bf16x8 qfrag[2];
#pragma unroll
    for (int kf = 0; kf < 2; ++kf) {
        int qr = wv * 16 + frow;
        int c16 = (kf * 4 + fk8) ^ (qr & 7);
        qfrag[kf] = *reinterpret_cast<const bf16x8*>((char*)Ks + qr * 128 + c16 * 16);
    }

    int voff[2];
#pragma unroll
    for (int i = 0; i < 2; ++i) {
        int c = (i * 4 + wv) * 64 + lane;
        int kb = c >> 5, db = (c >> 3) & 3, kr = (c >> 1) & 3, hf = c & 1;
        voff[i] = (kb * 4 + kr) * 64 + db * 16 + hf * 8;
    }

    u32 vta[4];
    {
        u32 vt0 = lds_addr(Vt) + fk8 * 1024 + frow * 2;
#pragma unroll
        for (int nf = 0; nf < 4; ++nf) vta[nf] = vt0 + nf * 128;
    }

    char* pwW = (char*)Pw + wv * 2048 + frow * 128 + (fk8 & 1) * 8;
    char* pwR = (char*)Pw + wv * 2048 + frow * 128;
    const float* mrow = mask + b * M_;

    float m_i = -1e30f, l_i = 0.f;
    const f32x4 z4 = {0.f, 0.f, 0.f, 0.f};
    f32x4 o_acc[4] = {z4, z4, z4, z4};

    for (int kt = 0; kt < 16; ++kt) {
        __syncthreads();
#pragma unroll
        for (int i = 0; i < 2; ++i) {
            int rr = (i * 4 + wv) * 8 + srr;
            int cc = (scc ^ (rr & 7)) * 8;
            gload16(K + base + (size_t)(kt * 64 + rr) * 64 + cc,
                    (char*)Ks + (i * 4 + wv) * 1024);
        }
#pragma unroll
        for (int i = 0; i < 2; ++i)
            gload16(V + base + kt * 4096 + voff[i], (char*)Vt + (i * 4 + wv) * 1024);
        asm volatile("s_waitcnt vmcnt(0)" ::: "memory");
        __syncthreads();

        f32x4 sacc[4] = {z4, z4, z4, z4};
        __builtin_amdgcn_s_setprio(1);
#pragma unroll
        for (int kf = 0; kf < 2; ++kf)
#pragma unroll
            for (int nf = 0; nf < 4; ++nf) {
                int kr = nf * 16 + frow;
                int c16 = (kf * 4 + fk8) ^ (kr & 7);
                bf16x8 ak = *reinterpret_cast<const bf16x8*>((char*)Ks + kr * 128 + c16 * 16);
                sacc[nf] = __builtin_amdgcn_mfma_f32_16x16x32_bf16(ak, qfrag[kf], sacc[nf], 0, 0, 0);
            }
        __builtin_amdgcn_s_setprio(0);

        float tval[4][4];
        float tmax = -1e30f;
#pragma unroll
        for (int nf = 0; nf < 4; ++nf) {
            float4 mk = *reinterpret_cast<const float4*>(mrow + kt * 64 + nf * 16 + fk8 * 4);
            float t0 = fmaf(sacc[nf][0], 0.125f, mk.x);
            float t1 = fmaf(sacc[nf][1], 0.125f, mk.y);
            float t2 = fmaf(sacc[nf][2], 0.125f, mk.z);
            float t3 = fmaf(sacc[nf][3], 0.125f, mk.w);
            tval[nf][0] = t0; tval[nf][1] = t1; tval[nf][2] = t2; tval[nf][3] = t3;
            tmax = fmaxf(tmax, fmaxf(fmaxf(t0, t1), fmaxf(t2, t3)));
        }
        tmax = fmaxf(tmax, __shfl_xor(tmax, 16));
        tmax = fmaxf(tmax, __shfl_xor(tmax, 32));

        if (__any(tmax > m_i + 8.f)) {
            float mnew = fmaxf(m_i, tmax);
            float c = exp2f((m_i - mnew) * LOG2E);
            m_i = mnew;
            l_i *= c;
#pragma unroll
            for (int j = 0; j < 4; ++j) {
                float cj = __shfl(c, fk8 * 4 + j);
#pragma unroll
                for (int nf = 0; nf < 4; ++nf) o_acc[nf][j] *= cj;
            }
        }

        const float ml = m_i * LOG2E;
        float rs = 0.f;
#pragma unroll
        for (int nf = 0; nf < 4; ++nf) {
            float p0 = exp2f(fmaf(tval[nf][0], LOG2E, -ml));
            float p1 = exp2f(fmaf(tval[nf][1], LOG2E, -ml));
            float p2 = exp2f(fmaf(tval[nf][2], LOG2E, -ml));
            float p3 = exp2f(fmaf(tval[nf][3], LOG2E, -ml));
            rs += (p0 + p1) + (p2 + p3);
            u32 w0 = __builtin_amdgcn_perm(__float_as_uint(p1), __float_as_uint(p0), 0x07060302u);
            u32 w1 = __builtin_amdgcn_perm(__float_as_uint(p3), __float_as_uint(p2), 0x07060302u);
            u32x2 wp = {w0, w1};
            *reinterpret_cast<u32x2*>(pwW + (((nf * 2 + (fk8 >> 1)) ^ (frow & 7)) * 16)) = wp;
        }
        rs += __shfl_xor(rs, 16);
        rs += __shfl_xor(rs, 32);
        l_i += rs;

#pragma unroll
        for (int kf = 0; kf < 2; ++kf) {
            bf16x8 ap = *reinterpret_cast<const bf16x8*>(pwR + (((kf * 4 + fk8) ^ (frow & 7)) * 16));
            u32x2 r0, r1, r2, r3, r4, r5, r6, r7;
            if (kf == 0) {
                asm volatile("ds_read_b64_tr_b16 %0, %1" : "=&v"(r0) : "v"(vta[0]));
                asm volatile("ds_read_b64_tr_b16 %0, %1 offset:512" : "=&v"(r1) : "v"(vta[0]));
                asm volatile("ds_read_b64_tr_b16 %0, %1" : "=&v"(r2) : "v"(vta[1]));
                asm volatile("ds_read_b64_tr_b16 %0, %1 offset:512" : "=&v"(r3) : "v"(vta[1]));
                asm volatile("ds_read_b64_tr_b16 %0, %1" : "=&v"(r4) : "v"(vta[2]));
                asm volatile("ds_read_b64_tr_b16 %0, %1 offset:512" : "=&v"(r5) : "v"(vta[2]));
                asm volatile("ds_read_b64_tr_b16 %0, %1" : "=&v"(r6) : "v"(vta[3]));
                asm volatile("ds_read_b64_tr_b16 %0, %1 offset:512" : "=&v"(r7) : "v"(vta[3]));
            } else {
                asm volatile("ds_read_b64_tr_b16 %0, %1 offset:4096" : "=&v"(r0) : "v"(vta[0]));
                asm volatile("ds_read_b64_tr_b16 %0, %1 offset:4608" : "=&v"(r1) : "v"(vta[0]));
                asm volatile("ds_read_b64_tr_b16 %0, %1 offset:4096" : "=&v"(r2) : "v"(vta[1]));
                asm volatile("ds_read_b64_tr_b16 %0, %1 offset:4608" : "=&v"(r3) : "v"(vta[1]));
                asm volatile("ds_read_b64_tr_b16 %0, %1 offset:4096" : "=&v"(r4) : "v"(vta[2]));
                asm volatile("ds_read_b64_tr_b16 %0, %1 offset:4608" : "=&v"(r5) : "v"(vta[2]));
                asm volatile("ds_read_b64_tr_b16 %0, %1 offset:4096" : "=&v"(r6) : "v"(vta[3]));
                asm volatile("ds_read_b64_tr_b16 %0, %1 offset:4608" : "=&v"(r7) : "v"(vta[3]));
            }
            asm volatile("s_waitcnt lgkmcnt(0)" ::: "memory");
            __builtin_amdgcn_sched_barrier(0);
            __builtin_amdgcn_s_setprio(1);
            {
                u32x4 vv = {r0.x, r0.y, r1.x, r1.y};
                bf16x8 fb; __builtin_memcpy(&fb, &vv, 16);
                o_acc[0] = __builtin_amdgcn_mfma_f32_16x16x32_bf16(ap, fb, o_acc[0], 0, 0, 0);
            }
            {
                u32x4 vv = {r2.x, r2.y, r3.x, r3.y};
                bf16x8 fb; __builtin_memcpy(&fb, &vv, 16);
                o_acc[1] = __builtin_amdgcn_mfma_f32_16x16x32_bf16(ap, fb, o_acc[1], 0, 0, 0);
            }
            {
                u32x4 vv = {r4.x, r4.y, r5.x, r5.y};
                bf16x8 fb; __builtin_memcpy(&fb, &vv, 16);
                o_acc[2] = __builtin_amdgcn_mfma_f32_16x16x32_bf16(ap, fb, o_acc[2], 0, 0, 0);
            }
            {
                u32x4 vv = {r6.x, r6.y, r7.x, r7.y};
                bf16x8 fb; __builtin_memcpy(&fb, &vv, 16);
                o_acc[3] = __builtin_amdgcn_mfma_f32_16x16x32_bf16(ap, fb, o_acc[3], 0, 0, 0);
            }
            __builtin_amdgcn_s_setprio(0);
        }
    }

#pragma unroll
    for (int j = 0; j < 4; ++j) {
        float lq = __shfl(l_i, fk8 * 4 + j);
        float inv = 1.f / lq;
        int grow = qt * 64 + wv * 16 + fk8 * 4 + j;
        size_t obase = ((size_t)(b * M_ + grow)) * DM_ + h * 64;
#pragma unroll
        for (int nf = 0; nf < 4; ++nf)
            O[obase + nf * 16 + frow] = f2bf(o_acc[nf][j] * inv);
    }
}

// ---------------------------------------------------------------------------
// LN over bf16 y with bf16 residual: out = LN(y + res + bias) * g + beta.
// MODE 0: emit bf16 (x1 path, in-place over res).  MODE 1: emit f32 (final).
// ---------------------------------------------------------------------------
template <int MODE>
__global__ __launch_bounds__(256) void ln_bf(const u16* __restrict__ y,
                                             const u16* __restrict__ resb,
                                             const float* __restrict__ bias,
                                             const float* __restrict__ g,
                                             const float* __restrict__ beta,
                                             float* __restrict__ outf,
                                             u16* __restrict__ outb) {
    __shared__ float red[2][4];
    const int row = blockIdx.x, tid = threadIdx.x;
    const size_t base = (size_t)row * 1024 + tid * 4;

    u32x2 yp = *reinterpret_cast<const u32x2*>(y + base);
    float v0 = bf2f((u16)(yp.x & 0xFFFF)), v1 = bf2f((u16)(yp.x >> 16));
    float v2 = bf2f((u16)(yp.y & 0xFFFF)), v3 = bf2f((u16)(yp.y >> 16));

    u32x2 rp = *reinterpret_cast<const u32x2*>(resb + base);
    float r0 = bf2f((u16)(rp.x & 0xFFFF)), r1 = bf2f((u16)(rp.x >> 16));
    float r2 = bf2f((u16)(rp.y & 0xFFFF)), r3 = bf2f((u16)(rp.y >> 16));

    float4 bb = *reinterpret_cast<const float4*>(bias + tid * 4);
    v0 += r0 + bb.x; v1 += r1 + bb.y; v2 += r2 + bb.z; v3 += r3 + bb.w;

    float sum = v0 + v1 + v2 + v3;
    float sq = v0 * v0 + v1 * v1 + v2 * v2 + v3 * v3;
#pragma unroll
    for (int off = 32; off; off >>= 1) {
        sum += __shfl_down(sum, off);
        sq += __shfl_down(sq, off);
    }
    if ((tid & 63) == 0) { red[0][tid >> 6] = sum; red[1][tid >> 6] = sq; }
    __syncthreads();
    sum = red[0][0] + red[0][1] + red[0][2] + red[0][3];
    sq = red[1][0] + red[1][1] + red[1][2] + red[1][3];
    float mu = sum * (1.f / 1024.f);
    float var = sq * (1.f / 1024.f) - mu * mu;
    float rstd = rsqrtf(var + 1e-12f);
    float4 gg = *reinterpret_cast<const float4*>(g + tid * 4);
    float4 be = *reinterpret_cast<const float4*>(beta + tid * 4);
    float o0 = (v0 - mu) * rstd * gg.x + be.x;
    float o1 = (v1 - mu) * rstd * gg.y + be.y;
    float o2 = (v2 - mu) * rstd * gg.z + be.z;
    float o3 = (v3 - mu) * rstd * gg.w + be.w;
    if (MODE == 1) {
        float4 o = {o0, o1, o2, o3};
        *reinterpret_cast<float4*>(outf + base) = o;
    } else {
        unsigned long long p = (unsigned long long)f2bf(o0)
                             | ((unsigned long long)f2bf(o1) << 16)
                             | ((unsigned long long)f2bf(o2) << 32)
                             | ((unsigned long long)f2bf(o3) << 48);
        *reinterpret_cast<unsigned long long*>(outb + base) = p;
    }
}

// ---------------------------------------------------------------------------
extern "C" void kernel_launch(void* const* d_in, const int* in_sizes, int n_in,
                              void* d_out, int out_size, void* d_ws, size_t ws_size,
                              hipStream_t stream) {
    const float* x    = (const float*)d_in[0];
    const float* mask = (const float*)d_in[1];
    const float* Pq   = (const float*)d_in[2];
    const float* Vq   = (const float*)d_in[3];
    const float* bq   = (const float*)d_in[4];
    const float* Pk   = (const float*)d_in[5];
    const float* Vk   = (const float*)d_in[6];
    const float* bk   = (const float*)d_in[7];
    const float* Pv   = (const float*)d_in[8];
    const float* Vv   = (const float*)d_in[9];
    const float* bv   = (const float*)d_in[10];
    const float* Uo   = (const float*)d_in[11];
    const float* Vo   = (const float*)d_in[12];
    const float* bo   = (const float*)d_in[13];
    const float* g1   = (const float*)d_in[14];
    const float* be1  = (const float*)d_in[15];
    const float* U1   = (const float*)d_in[16];
    const float* V1   = (const float*)d_in[17];
    const float* b1   = (const float*)d_in[18];
    const float* U2   = (const float*)d_in[19];
    const float* V2   = (const float*)d_in[20];
    const float* b2   = (const float*)d_in[21];
    const float* g2   = (const float*)d_in[22];
    const float* be2  = (const float*)d_in[23];
    float* out = (float*)d_out;

    const size_t MB = 1048576;
    char* ws = (char*)d_ws;
    u16* Pt  = (u16*)(ws + 0);                 // 3 MB (1536 x 1024 bf16)
    u16* Ftq = (u16*)(ws + 3 * MB);
    u16* Ftk = (u16*)(ws + 3 * MB + 131072);
    u16* Ftv = (u16*)(ws + 3 * MB + 262144);
    u16* Uot = (u16*)(ws + 4 * MB);            // 1 MB (512 x 1024)
    u16* Vot = (u16*)(ws + 5 * MB);            // 1 MB (1024 x 512)
    u16* U1t = (u16*)(ws + 6 * MB);            // 1 MB (512 x 1024)
    u16* V1t = (u16*)(ws + 7 * MB);            // 4 MB (4096 x 512)
    u16* U2t = (u16*)(ws + 11 * MB);           // 4 MB (512 x 4096)
    u16* V2t = (u16*)(ws + 15 * MB);           // 1 MB (1024 x 512)
    u16* Xb  = (u16*)(ws + 16 * MB);           // 16 MB (x bf16; later x1 bf16)
    u16* Qb  = (u16*)(ws + 56 * MB);           // 16 MB
    u16* Kb  = (u16*)(ws + 72 * MB);           // 16 MB
    u16* Vb  = (u16*)(ws + 88 * MB);           // 16 MB
    u16* Ob  = (u16*)(ws + 104 * MB);          // 16 MB
    u16* Hb  = (u16*)(ws + 32 * MB);           // 64 MB (reuses Q/K/V area later)
    u16* Yb  = (u16*)(ws + 56 * MB);           // 16 MB bf16 y (reuses Qb)
    u16* Tb  = (u16*)(ws + 96 * MB);           // 8 MB (8192 x 512 bf16)

    // --- all precompute in one launch ---
    prep_all<<<4016, 256, 0, stream>>>(x, Pq, Pk, Pv, Vq, Vk, Vv,
                                       Uo, Vo, U1, V1, U2, V2,
                                       Xb, Pt, Ftq, Ftk, Ftv,
                                       Uot, Vot, U1t, V1t, U2t, V2t);

    // --- QKV: one fused GEMM (stage-1 matmul + per-head rank-32 epilogue) ---
    gemm_qkv<<<dim3(12, 64), 256, 0, stream>>>(Xb, Pt, Ftq, Ftk, Ftv,
                                               bq, bk, bv, Qb, Kb, Vb);

    // --- attention ---
    attn_mfma<<<2048, 256, 0, stream>>>(Qb, Kb, Vb, mask, Ob);

    // --- attn out proj + LN1 (bf16 y, bf16 residual from Xb) ---
    gemm_db<<<dim3(8, 64), 256, 0, stream>>>(Ob, Uot, Tb, 1024, 512);
    gemm_bf16<0, 4><<<dim3(8, 64), 256, 0, stream>>>(Tb, Vot, nullptr, Yb, 512, 1024);
    ln_bf<0><<<8192, 256, 0, stream>>>(Yb, Xb, bo, g1, be1, nullptr, Xb);

    // --- FFN + LN2 ---
    gemm_db<<<dim3(8, 64), 256, 0, stream>>>(Xb, U1t, Tb, 1024, 512);
    // mid@V1 + bias + gelu via the 8-phase 256^2 kernel
    gemm_8ph<<<dim3(16, 32), 512, 0, stream>>>(Tb, V1t, b1, Hb);
    gemm_db<<<dim3(8, 64), 256, 0, stream>>>(Hb, U2t, Tb, 4096, 512);
    gemm_bf16<0, 4><<<dim3(8, 64), 256, 0, stream>>>(Tb, V2t, nullptr, Yb, 512, 1024);
    ln_bf<1><<<8192, 256, 0, stream>>>(Yb, Xb, b2, g2, be2, out, nullptr);
}

// Round 12
// 337.595 us; speedup vs baseline: 1.0139x; 1.0139x over previous
//
#include <hip/hip_runtime.h>
#include <hip/hip_bf16.h>
#include <math.h>

typedef unsigned short u16;
typedef unsigned int u32;
typedef __attribute__((ext_vector_type(8))) short bf16x8;
typedef __attribute__((ext_vector_type(4))) float f32x4;
typedef __attribute__((ext_vector_type(2))) unsigned int u32x2;
typedef __attribute__((ext_vector_type(4))) unsigned int u32x4;

#define B_ 8
#define M_ 1024
#define DM_ 1024
#define H_ 16
#define DH_ 64
#define NR_ 8192

__device__ __forceinline__ u16 f2bf(float f) {
    unsigned u = __float_as_uint(f);
    u += 0x7FFFu + ((u >> 16) & 1u);
    return (u16)(u >> 16);
}

__device__ __forceinline__ float bf2f(u16 v) {
    return __uint_as_float((u32)v << 16);
}

__device__ __forceinline__ void gload16(const void* g, void* l) {
    __builtin_amdgcn_global_load_lds(
        (const __attribute__((address_space(1))) void*)g,
        (__attribute__((address_space(3))) void*)l, 16, 0, 0);
}

__device__ __forceinline__ u32 lds_addr(const void* p) {
    return (u32)(uintptr_t)(const __attribute__((address_space(3))) void*)p;
}

// fast exact-enough gelu: Abramowitz-Stegun 7.1.26 erf (|eps| < 1.5e-7)
__device__ __forceinline__ float gelu_f(float x) {
    float ax = fabsf(x);
    float t = 1.f / fmaf(0.3275911f, ax, 1.f);
    float poly = t * fmaf(t, fmaf(t, fmaf(t, fmaf(t, 1.061405429f, -1.453152027f),
                                          1.421413741f), -0.284496736f), 0.254829592f);
    float er = 1.f - poly * __expf(-ax * ax);
    er = copysignf(er, x);
    return 0.5f * x * (1.f + er);
}

// ---------------------------------------------------------------------------
// Mega-prep: x->bf16, P transposes, V-factor transposes, Uo bf16 copy,
// and the remaining weight transposes.
// ---------------------------------------------------------------------------
__device__ void conv_dev(const float* __restrict__ in, u16* __restrict__ out,
                         int bid, int tid) {
#pragma unroll
    for (int j = 0; j < 4; ++j) {
        int i = bid * 4096 + j * 1024 + tid * 4;
        float4 v = *reinterpret_cast<const float4*>(in + i);
        unsigned long long p = (unsigned long long)f2bf(v.x)
                             | ((unsigned long long)f2bf(v.y) << 16)
                             | ((unsigned long long)f2bf(v.z) << 32)
                             | ((unsigned long long)f2bf(v.w) << 48);
        *reinterpret_cast<unsigned long long*>(out + i) = p;
    }
}

__device__ void prep_p_dev(const float* __restrict__ P, u16* __restrict__ Pt,
                           int h, int kc, int tid, float* sm) {
    float (*Ps)[33] = (float(*)[33])sm;
#pragma unroll
    for (int i = 0; i < 16; ++i) {
        int e = tid + i * 256;
        int kk = e >> 5, r = e & 31;
        Ps[kk][r] = P[(size_t)h * 32768 + (size_t)(kc + kk) * 32 + r];
    }
    __syncthreads();
#pragma unroll
    for (int i = 0; i < 16; ++i) {
        int e = tid + i * 256;
        int r = e >> 7, k = e & 127;
        Pt[(size_t)(h * 32 + r) * 1024 + kc + k] = f2bf(Ps[k][r]);
    }
}

__device__ void prep_f_dev(const float* __restrict__ V, u16* __restrict__ Ft,
                           int h, int tid, float* sm) {
    float (*Vs)[65] = (float(*)[65])sm;
#pragma unroll
    for (int i = 0; i < 8; ++i) {
        int e = tid + i * 256;
        int r = e >> 6, c = e & 63;
        Vs[r][c] = V[(size_t)h * 2048 + r * 64 + c];
    }
    __syncthreads();
#pragma unroll
    for (int i = 0; i < 8; ++i) {
        int idx = tid + i * 256;
        int e = idx >> 5, r = idx & 31;
        Ft[(size_t)h * 2560 + e * 40 + r] = f2bf(Vs[r][e]);
    }
}

__device__ void transp_dev(const float* __restrict__ in, u16* __restrict__ out,
                           int R, int C, int bx, int by, int tid, float* sm) {
    float (*t)[65] = (float(*)[65])sm;
    const int rb = by * 64, cb = bx * 64;
#pragma unroll
    for (int i = 0; i < 16; ++i) {
        int e = tid + i * 256;
        int r = e >> 6, c = e & 63;
        t[r][c] = in[(size_t)(rb + r) * C + cb + c];
    }
    __syncthreads();
#pragma unroll
    for (int i = 0; i < 16; ++i) {
        int e = tid + i * 256;
        int r = e >> 6, c = e & 63;
        out[(size_t)(cb + r) * R + rb + c] = f2bf(t[c][r]);
    }
}

__global__ __launch_bounds__(256) void prep_all(
    const float* __restrict__ x,
    const float* __restrict__ Pq, const float* __restrict__ Pk, const float* __restrict__ Pv,
    const float* __restrict__ Vq, const float* __restrict__ Vk, const float* __restrict__ Vv,
    const float* __restrict__ Uo, const float* __restrict__ Vo,
    const float* __restrict__ U1, const float* __restrict__ V1,
    const float* __restrict__ U2, const float* __restrict__ V2,
    u16* __restrict__ Xb, u16* __restrict__ Pt,
    u16* __restrict__ Ftq, u16* __restrict__ Ftk, u16* __restrict__ Ftv,
    u16* __restrict__ Uob, u16* __restrict__ Vot,
    u16* __restrict__ U1t, u16* __restrict__ V1t,
    u16* __restrict__ U2t, u16* __restrict__ V2t) {
    __shared__ float smem[4224];
    const int bid = blockIdx.x, tid = threadIdx.x;
    if (bid < 2048) {
        conv_dev(x, Xb, bid, tid);
    } else if (bid < 2432) {
        int t = bid - 2048, which = t >> 7, tt = t & 127;
        const float* P = which == 0 ? Pq : (which == 1 ? Pk : Pv);
        prep_p_dev(P, Pt + (size_t)which * 524288, tt >> 3, (tt & 7) * 128, tid, smem);
    } else if (bid < 2480) {
        int t = bid - 2432, which = t >> 4;
        const float* V = which == 0 ? Vq : (which == 1 ? Vk : Vv);
        u16* F = which == 0 ? Ftq : (which == 1 ? Ftk : Ftv);
        prep_f_dev(V, F, t & 15, tid, smem);
    } else if (bid < 2608) {
        // Uo (1024 x 512) -> straight bf16 copy (B-operand of the Wot build)
        conv_dev(Uo, Uob, bid - 2480, tid);
    } else if (bid < 2736) {
        int t = bid - 2608;
        transp_dev(Vo, Vot, 512, 1024, t & 15, t >> 4, tid, smem);
    } else if (bid < 2864) {
        int t = bid - 2736;
        transp_dev(U1, U1t, 1024, 512, t & 7, t >> 3, tid, smem);
    } else if (bid < 3376) {
        int t = bid - 2864;
        transp_dev(V1, V1t, 512, 4096, t & 63, t >> 6, tid, smem);
    } else if (bid < 3888) {
        int t = bid - 3376;
        transp_dev(U2, U2t, 4096, 512, t & 7, t >> 3, tid, smem);
    } else {
        int t = bid - 3888;
        transp_dev(V2, V2t, 512, 1024, t & 15, t >> 4, tid, smem);
    }
}

// ---------------------------------------------------------------------------
// bf16 MFMA GEMM (single-buffer): C(M x N) = A(M x K) @ Bt(N x K)^T
// M = gridDim.y * 128.  EPI: 0 bf16, 2 bias+gelu bf16.
// ---------------------------------------------------------------------------
template <int EPI, int NF>
__global__ __launch_bounds__(256) void gemm_bf16(const u16* __restrict__ A,
                                                 const u16* __restrict__ Bt,
                                                 const float* __restrict__ bias,
                                                 void* __restrict__ Cout,
                                                 int K, int N) {
    constexpr int BN = NF * 32;
    __shared__ u16 As[128 * 64];
    __shared__ u16 Bs[BN * 64];
    const int tid = threadIdx.x;
    const int lane = tid & 63, wv = tid >> 6;

    const int NX = gridDim.x;
    const int flat = blockIdx.x + blockIdx.y * NX;
    const int q = (NX * gridDim.y) >> 3;
    const int nid = (flat & 7) * q + (flat >> 3);
    const int row0 = (nid / NX) * 128, col0 = (nid % NX) * BN;

    const int frow = lane & 15, fk8 = lane >> 4;
    const int wm = (wv >> 1) * 64, wn = (wv & 1) * (BN / 2);

    f32x4 acc[4][NF];
    const f32x4 z4 = {0.f, 0.f, 0.f, 0.f};
#pragma unroll
    for (int i = 0; i < 4; ++i)
#pragma unroll
        for (int j = 0; j < NF; ++j) acc[i][j] = z4;

    for (int k0 = 0; k0 < K; k0 += 64) {
#pragma unroll
        for (int i = 0; i < 4; ++i) {
            int rr = (i * 4 + wv) * 8 + (lane >> 3);
            int cc = ((lane & 7) ^ (rr & 7)) * 8;
            gload16(A + (size_t)(row0 + rr) * K + k0 + cc,
                    (char*)As + (i * 4 + wv) * 1024);
        }
#pragma unroll
        for (int i = 0; i < NF; ++i) {
            int rr = (i * 4 + wv) * 8 + (lane >> 3);
            int cc = ((lane & 7) ^ (rr & 7)) * 8;
            gload16(Bt + (size_t)(col0 + rr) * K + k0 + cc,
                    (char*)Bs + (i * 4 + wv) * 1024);
        }
        asm volatile("s_waitcnt vmcnt(0)" ::: "memory");
        __syncthreads();
#pragma unroll
        for (int kf = 0; kf < 2; ++kf) {
            bf16x8 af[4], bfr[NF];
#pragma unroll
            for (int mf = 0; mf < 4; ++mf) {
                int r = wm + mf * 16 + frow;
                int c16 = (kf * 4 + fk8) ^ (r & 7);
                af[mf] = *reinterpret_cast<const bf16x8*>((char*)As + r * 128 + c16 * 16);
            }
#pragma unroll
            for (int nf = 0; nf < NF; ++nf) {
                int r = wn + nf * 16 + frow;
                int c16 = (kf * 4 + fk8) ^ (r & 7);
                bfr[nf] = *reinterpret_cast<const bf16x8*>((char*)Bs + r * 128 + c16 * 16);
            }
#pragma unroll
            for (int mf = 0; mf < 4; ++mf)
#pragma unroll
                for (int nf = 0; nf < NF; ++nf)
                    acc[mf][nf] = __builtin_amdgcn_mfma_f32_16x16x32_bf16(
                        af[mf], bfr[nf], acc[mf][nf], 0, 0, 0);
        }
        __syncthreads();
    }

    const int orow = fk8 * 4, ocol = frow;
#pragma unroll
    for (int mf = 0; mf < 4; ++mf)
#pragma unroll
        for (int nf = 0; nf < NF; ++nf)
#pragma unroll
            for (int j = 0; j < 4; ++j) {
                int row = row0 + wm + mf * 16 + orow + j;
                int col = col0 + wn + nf * 16 + ocol;
                float v = acc[mf][nf][j];
                if (EPI == 2) {
                    v += bias[col];
                    v = gelu_f(v);
                    ((u16*)Cout)[(size_t)row * N + col] = f2bf(v);
                } else {
                    ((u16*)Cout)[(size_t)row * N + col] = f2bf(v);
                }
            }
}

// ---------------------------------------------------------------------------
// QKV fused GEMM: stage-1 matmul kept in regs, per-head rank-32 transform in
// the epilogue via wave-local LDS transpose, direct Q/K/V (+bias) scatter.
// ---------------------------------------------------------------------------
__global__ __launch_bounds__(256) void gemm_qkv(const u16* __restrict__ A,
                                                const u16* __restrict__ Bt,
                                                const u16* __restrict__ Ftq,
                                                const u16* __restrict__ Ftk,
                                                const u16* __restrict__ Ftv,
                                                const float* __restrict__ bq,
                                                const float* __restrict__ bk,
                                                const float* __restrict__ bv,
                                                u16* __restrict__ Qo,
                                                u16* __restrict__ Ko,
                                                u16* __restrict__ Vo) {
    const int K = 1024;
    __shared__ u16 As[128 * 64];
    __shared__ u16 Bs[128 * 64];
    const int tid = threadIdx.x;
    const int lane = tid & 63, wv = tid >> 6;

    const int NX = gridDim.x;
    const int flat = blockIdx.x + blockIdx.y * NX;
    const int q = (NX * gridDim.y) >> 3;
    const int nid = (flat & 7) * q + (flat >> 3);
    const int row0 = (nid / NX) * 128, col0 = (nid % NX) * 128;

    const int frow = lane & 15, fk8 = lane >> 4;
    const int wm = (wv >> 1) * 64, wn = (wv & 1) * 64;

    f32x4 acc[4][4];
    const f32x4 z4 = {0.f, 0.f, 0.f, 0.f};
#pragma unroll
    for (int i = 0; i < 4; ++i)
#pragma unroll
        for (int j = 0; j < 4; ++j) acc[i][j] = z4;

    for (int k0 = 0; k0 < K; k0 += 64) {
#pragma unroll
        for (int i = 0; i < 4; ++i) {
            int rr = (i * 4 + wv) * 8 + (lane >> 3);
            int cc = ((lane & 7) ^ (rr & 7)) * 8;
            gload16(A + (size_t)(row0 + rr) * K + k0 + cc,
                    (char*)As + (i * 4 + wv) * 1024);
            gload16(Bt + (size_t)(col0 + rr) * K + k0 + cc,
                    (char*)Bs + (i * 4 + wv) * 1024);
        }
        asm volatile("s_waitcnt vmcnt(0)" ::: "memory");
        __syncthreads();
#pragma unroll
        for (int kf = 0; kf < 2; ++kf) {
            bf16x8 af[4], bfr[4];
#pragma unroll
            for (int mf = 0; mf < 4; ++mf) {
                int r = wm + mf * 16 + frow;
                int c16 = (kf * 4 + fk8) ^ (r & 7);
                af[mf] = *reinterpret_cast<const bf16x8*>((char*)As + r * 128 + c16 * 16);
            }
#pragma unroll
            for (int nf = 0; nf < 4; ++nf) {
                int r = wn + nf * 16 + frow;
                int c16 = (kf * 4 + fk8) ^ (r & 7);
                bfr[nf] = *reinterpret_cast<const bf16x8*>((char*)Bs + r * 128 + c16 * 16);
            }
#pragma unroll
            for (int mf = 0; mf < 4; ++mf)
#pragma unroll
                for (int nf = 0; nf < 4; ++nf)
                    acc[mf][nf] = __builtin_amdgcn_mfma_f32_16x16x32_bf16(
                        af[mf], bfr[nf], acc[mf][nf], 0, 0, 0);
        }
        __syncthreads();
    }

    // --- epilogue: per-head rank-32 transform -------------------------------
    u16* preg = (wv < 2) ? As + wv * 4096 : Bs + (wv - 2) * 4096;
#pragma unroll
    for (int mf = 0; mf < 4; ++mf)
#pragma unroll
        for (int nf = 0; nf < 4; ++nf)
#pragma unroll
            for (int j = 0; j < 4; ++j) {
                int r = mf * 16 + fk8 * 4 + j;
                int c = nf * 16 + frow;
                int byte = r * 128 + (((c >> 3) ^ (r & 7)) * 16) + (c & 7) * 2;
                *(u16*)((char*)preg + byte) = f2bf(acc[mf][nf][j]);
            }
    __syncthreads();

    const int f = col0 >> 9;                       // 0=q, 1=k, 2=v
    const u16* Ft = f == 0 ? Ftq : (f == 1 ? Ftk : Ftv);
    const float* bias = f == 0 ? bq : (f == 1 ? bk : bv);
    u16* outp = f == 0 ? Qo : (f == 1 ? Ko : Vo);
    const int h0 = (((col0 & 511) + wn) >> 5);

#pragma unroll
    for (int hh = 0; hh < 2; ++hh) {
        const int h = h0 + hh;
        const u16* ftb = Ft + (size_t)h * 2560;
        bf16x8 bf2[4];
#pragma unroll
        for (int ef = 0; ef < 4; ++ef) {
            int e = ef * 16 + frow;
            bf2[ef] = *reinterpret_cast<const bf16x8*>(ftb + e * 40 + fk8 * 8);
        }
#pragma unroll
        for (int mf = 0; mf < 4; ++mf) {
            int r = mf * 16 + frow;
            bf16x8 af = *reinterpret_cast<const bf16x8*>(
                (char*)preg + r * 128 + (((hh * 4 + fk8) ^ (r & 7)) * 16));
#pragma unroll
            for (int ef = 0; ef < 4; ++ef) {
                f32x4 o = __builtin_amdgcn_mfma_f32_16x16x32_bf16(af, bf2[ef], z4, 0, 0, 0);
                int e = ef * 16 + frow;
                float bv_ = bias[h * 64 + e];
#pragma unroll
                for (int j = 0; j < 4; ++j) {
                    int row = row0 + wm + mf * 16 + fk8 * 4 + j;
                    int bb = row >> 10, m = row & 1023;
                    outp[(((size_t)(bb * 16 + h) << 10) + m) * 64 + e] = f2bf(o[j] + bv_);
                }
            }
        }
    }
}

// ---------------------------------------------------------------------------
// Double-buffered prefetch GEMM for N=512 outputs (BN=64, bf16 out).
// ---------------------------------------------------------------------------
__global__ __launch_bounds__(256) void gemm_db(const u16* __restrict__ A,
                                               const u16* __restrict__ Bt,
                                               u16* __restrict__ Cout,
                                               int K, int N) {
    __shared__ u16 As[2][128 * 64];
    __shared__ u16 Bs[2][64 * 64];
    const int tid = threadIdx.x;
    const int lane = tid & 63, wv = tid >> 6;

    const int NX = gridDim.x;
    const int flat = blockIdx.x + blockIdx.y * NX;
    const int q = (NX * gridDim.y) >> 3;
    const int nid = (flat & 7) * q + (flat >> 3);
    const int row0 = (nid / NX) * 128, col0 = (nid % NX) * 64;

    const int frow = lane & 15, fk8 = lane >> 4;
    const int wm = (wv >> 1) * 64, wn = (wv & 1) * 32;

    f32x4 acc[4][2];
    const f32x4 z4 = {0.f, 0.f, 0.f, 0.f};
#pragma unroll
    for (int i = 0; i < 4; ++i) {
        acc[i][0] = z4;
        acc[i][1] = z4;
    }

    const int srr = (lane >> 3);
    const int scc = (lane & 7);

#pragma unroll
    for (int i = 0; i < 4; ++i) {
        int rr = (i * 4 + wv) * 8 + srr;
        int cc = (scc ^ (rr & 7)) * 8;
        gload16(A + (size_t)(row0 + rr) * K + cc, (char*)&As[0][0] + (i * 4 + wv) * 1024);
    }
#pragma unroll
    for (int i = 0; i < 2; ++i) {
        int rr = (i * 4 + wv) * 8 + srr;
        int cc = (scc ^ (rr & 7)) * 8;
        gload16(Bt + (size_t)(col0 + rr) * K + cc, (char*)&Bs[0][0] + (i * 4 + wv) * 1024);
    }

    int cur = 0;
    for (int k0 = 0; k0 < K; k0 += 64) {
        __syncthreads();
        if (k0 + 64 < K) {
            int kn = k0 + 64;
#pragma unroll
            for (int i = 0; i < 4; ++i) {
                int rr = (i * 4 + wv) * 8 + srr;
                int cc = (scc ^ (rr & 7)) * 8;
                gload16(A + (size_t)(row0 + rr) * K + kn + cc,
                        (char*)&As[cur ^ 1][0] + (i * 4 + wv) * 1024);
            }
#pragma unroll
            for (int i = 0; i < 2; ++i) {
                int rr = (i * 4 + wv) * 8 + srr;
                int cc = (scc ^ (rr & 7)) * 8;
                gload16(Bt + (size_t)(col0 + rr) * K + kn + cc,
                        (char*)&Bs[cur ^ 1][0] + (i * 4 + wv) * 1024);
            }
        }
#pragma unroll
        for (int kf = 0; kf < 2; ++kf) {
            bf16x8 af[4], bfr[2];
#pragma unroll
            for (int mf = 0; mf < 4; ++mf) {
                int r = wm + mf * 16 + frow;
                int c16 = (kf * 4 + fk8) ^ (r & 7);
                af[mf] = *reinterpret_cast<const bf16x8*>((char*)&As[cur][0] + r * 128 + c16 * 16);
            }
#pragma unroll
            for (int nf = 0; nf < 2; ++nf) {
                int r = wn + nf * 16 + frow;
                int c16 = (kf * 4 + fk8) ^ (r & 7);
                bfr[nf] = *reinterpret_cast<const bf16x8*>((char*)&Bs[cur][0] + r * 128 + c16 * 16);
            }
#pragma unroll
            for (int mf = 0; mf < 4; ++mf)
#pragma unroll
                for (int nf = 0; nf < 2; ++nf)
                    acc[mf][nf] = __builtin_amdgcn_mfma_f32_16x16x32_bf16(
                        af[mf], bfr[nf], acc[mf][nf], 0, 0, 0);
        }
        cur ^= 1;
    }

#pragma unroll
    for (int mf = 0; mf < 4; ++mf)
#pragma unroll
        for (int nf = 0; nf < 2; ++nf)
#pragma unroll
            for (int j = 0; j < 4; ++j) {
                int row = row0 + wm + mf * 16 + fk8 * 4 + j;
                int col = col0 + wn + nf * 16 + frow;
                Cout[(size_t)row * N + col] = f2bf(acc[mf][nf][j]);
            }
}

// ---------------------------------------------------------------------------
// MFMA flash attention — round-5 variant (best measured: 92 us).
// ---------------------------------------------------------------------------
__global__ __launch_bounds__(256) void attn_mfma(const u16* __restrict__ Q,
                                                 const u16* __restrict__ K,
                                                 const u16* __restrict__ V,
                                                 const float* __restrict__ mask,
                                                 u16* __restrict__ O) {
    __shared__ u16 Ks[4096];
    __shared__ u16 Vt[4096];
    __shared__ u16 Pw[4096];
    const int flat = blockIdx.x;
    const int nid = (flat & 7) * 256 + (flat >> 3);
    const int hb = nid >> 4, qt = nid & 15;
    const int b = hb >> 4, h = hb & 15;
    const int tid = threadIdx.x, lane = tid & 63, wv = tid >> 6;
    const int frow = lane & 15, fk8 = lane >> 4;
    const size_t base = (size_t)hb * 65536;
    const float LOG2E = 1.44269504089f;
    const int srr = lane >> 3, scc = lane & 7;

#pragma unroll
    for (int i = 0; i < 2; ++i) {
        int rr = (i * 4 + wv) * 8 + srr;
        int cc = (scc ^ (rr & 7)) * 8;
        gload16(Q + base + (size_t)(qt * 64 + rr) * 64 + cc,
                (char*)Ks + (i * 4 + wv) * 1024);
    }
    asm volatile("s_waitcnt vmcnt(0)" ::: "memory");
    __syncthreads();
    bf16x8 qfrag[2];
#pragma unroll
    for (int kf = 0; kf < 2; ++kf) {
        int qr = wv * 16 + frow;
        int c16 = (kf * 4 + fk8) ^ (qr & 7);
        qfrag[kf] = *reinterpret_cast<const bf16x8*>((char*)Ks + qr * 128 + c16 * 16);
    }

    int voff[2];
#pragma unroll
    for (int i = 0; i < 2; ++i) {
        int c = (i * 4 + wv) * 64 + lane;
        int kb = c >> 5, db = (c >> 3) & 3, kr = (c >> 1) & 3, hf = c & 1;
        voff[i] = (kb * 4 + kr) * 64 + db * 16 + hf * 8;
    }

    u32 vta[4];
    {
        u32 vt0 = lds_addr(Vt) + fk8 * 1024 + frow * 2;
#pragma unroll
        for (int nf = 0; nf < 4; ++nf) vta[nf] = vt0 + nf * 128;
    }

    char* pwW = (char*)Pw + wv * 2048 + frow * 128 + (fk8 & 1) * 8;
    char* pwR = (char*)Pw + wv * 2048 + frow * 128;
    const float* mrow = mask + b * M_;

    float m_i = -1e30f, l_i = 0.f;
    const f32x4 z4 = {0.f, 0.f, 0.f, 0.f};
    f32x4 o_acc[4] = {z4, z4, z4, z4};

    for (int kt = 0; kt < 16; ++kt) {
        __syncthreads();
#pragma unroll
        for (int i = 0; i < 2; ++i) {
            int rr = (i * 4 + wv) * 8 + srr;
            int cc = (scc ^ (rr & 7)) * 8;
            gload16(K + base + (size_t)(kt * 64 + rr) * 64 + cc,
                    (char*)Ks + (i * 4 + wv) * 1024);
        }
#pragma unroll
        for (int i = 0; i < 2; ++i)
            gload16(V + base + kt * 4096 + voff[i], (char*)Vt + (i * 4 + wv) * 1024);
        asm volatile("s_waitcnt vmcnt(0)" ::: "memory");
        __syncthreads();

        f32x4 sacc[4] = {z4, z4, z4, z4};
        __builtin_amdgcn_s_setprio(1);
#pragma unroll
        for (int kf = 0; kf < 2; ++kf)
#pragma unroll
            for (int nf = 0; nf < 4; ++nf) {
                int kr = nf * 16 + frow;
                int c16 = (kf * 4 + fk8) ^ (kr & 7);
                bf16x8 ak = *reinterpret_cast<const bf16x8*>((char*)Ks + kr * 128 + c16 * 16);
                sacc[nf] = __builtin_amdgcn_mfma_f32_16x16x32_bf16(ak, qfrag[kf], sacc[nf], 0, 0, 0);
            }
        __builtin_amdgcn_s_setprio(0);

        float tval[4][4];
        float tmax = -1e30f;
#pragma unroll
        for (int nf = 0; nf < 4; ++nf) {
            float4 mk = *reinterpret_cast<const float4*>(mrow + kt * 64 + nf * 16 + fk8 * 4);
            float t0 = fmaf(sacc[nf][0], 0.125f, mk.x);
            float t1 = fmaf(sacc[nf][1], 0.125f, mk.y);
            float t2 = fmaf(sacc[nf][2], 0.125f, mk.z);
            float t3 = fmaf(sacc[nf][3], 0.125f, mk.w);
            tval[nf][0] = t0; tval[nf][1] = t1; tval[nf][2] = t2; tval[nf][3] = t3;
            tmax = fmaxf(tmax, fmaxf(fmaxf(t0, t1), fmaxf(t2, t3)));
        }
        tmax = fmaxf(tmax, __shfl_xor(tmax, 16));
        tmax = fmaxf(tmax, __shfl_xor(tmax, 32));

        if (__any(tmax > m_i + 8.f)) {
            float mnew = fmaxf(m_i, tmax);
            float c = exp2f((m_i - mnew) * LOG2E);
            m_i = mnew;
            l_i *= c;
#pragma unroll
            for (int j = 0; j < 4; ++j) {
                float cj = __shfl(c, fk8 * 4 + j);
#pragma unroll
                for (int nf = 0; nf < 4; ++nf) o_acc[nf][j] *= cj;
            }
        }

        const float ml = m_i * LOG2E;
        float rs = 0.f;
#pragma unroll
        for (int nf = 0; nf < 4; ++nf) {
            float p0 = exp2f(fmaf(tval[nf][0], LOG2E, -ml));
            float p1 = exp2f(fmaf(tval[nf][1], LOG2E, -ml));
            float p2 = exp2f(fmaf(tval[nf][2], LOG2E, -ml));
            float p3 = exp2f(fmaf(tval[nf][3], LOG2E, -ml));
            rs += (p0 + p1) + (p2 + p3);
            u32 w0 = __builtin_amdgcn_perm(__float_as_uint(p1), __float_as_uint(p0), 0x07060302u);
            u32 w1 = __builtin_amdgcn_perm(__float_as_uint(p3), __float_as_uint(p2), 0x07060302u);
            u32x2 wp = {w0, w1};
            *reinterpret_cast<u32x2*>(pwW + (((nf * 2 + (fk8 >> 1)) ^ (frow & 7)) * 16)) = wp;
        }
        rs += __shfl_xor(rs, 16);
        rs += __shfl_xor(rs, 32);
        l_i += rs;

#pragma unroll
        for (int kf = 0; kf < 2; ++kf) {
            bf16x8 ap = *reinterpret_cast<const bf16x8*>(pwR + (((kf * 4 + fk8) ^ (frow & 7)) * 16));
            u32x2 r0, r1, r2, r3, r4, r5, r6, r7;
            if (kf == 0) {
                asm volatile("ds_read_b64_tr_b16 %0, %1" : "=&v"(r0) : "v"(vta[0]));
                asm volatile("ds_read_b64_tr_b16 %0, %1 offset:512" : "=&v"(r1) : "v"(vta[0]));
                asm volatile("ds_read_b64_tr_b16 %0, %1" : "=&v"(r2) : "v"(vta[1]));
                asm volatile("ds_read_b64_tr_b16 %0, %1 offset:512" : "=&v"(r3) : "v"(vta[1]));
                asm volatile("ds_read_b64_tr_b16 %0, %1" : "=&v"(r4) : "v"(vta[2]));
                asm volatile("ds_read_b64_tr_b16 %0, %1 offset:512" : "=&v"(r5) : "v"(vta[2]));
                asm volatile("ds_read_b64_tr_b16 %0, %1" : "=&v"(r6) : "v"(vta[3]));
                asm volatile("ds_read_b64_tr_b16 %0, %1 offset:512" : "=&v"(r7) : "v"(vta[3]));
            } else {
                asm volatile("ds_read_b64_tr_b16 %0, %1 offset:4096" : "=&v"(r0) : "v"(vta[0]));
                asm volatile("ds_read_b64_tr_b16 %0, %1 offset:4608" : "=&v"(r1) : "v"(vta[0]));
                asm volatile("ds_read_b64_tr_b16 %0, %1 offset:4096" : "=&v"(r2) : "v"(vta[1]));
                asm volatile("ds_read_b64_tr_b16 %0, %1 offset:4608" : "=&v"(r3) : "v"(vta[1]));
                asm volatile("ds_read_b64_tr_b16 %0, %1 offset:4096" : "=&v"(r4) : "v"(vta[2]));
                asm volatile("ds_read_b64_tr_b16 %0, %1 offset:4608" : "=&v"(r5) : "v"(vta[2]));
                asm volatile("ds_read_b64_tr_b16 %0, %1 offset:4096" : "=&v"(r6) : "v"(vta[3]));
                asm volatile("ds_read_b64_tr_b16 %0, %1 offset:4608" : "=&v"(r7) : "v"(vta[3]));
            }
            asm volatile("s_waitcnt lgkmcnt(0)" ::: "memory");
            __builtin_amdgcn_sched_barrier(0);
            __builtin_amdgcn_s_setprio(1);
            {
                u32x4 vv = {r0.x, r0.y, r1.x, r1.y};
                bf16x8 fb; __builtin_memcpy(&fb, &vv, 16);
                o_acc[0] = __builtin_amdgcn_mfma_f32_16x16x32_bf16(ap, fb, o_acc[0], 0, 0, 0);
            }
            {
                u32x4 vv = {r2.x, r2.y, r3.x, r3.y};
                bf16x8 fb; __builtin_memcpy(&fb, &vv, 16);
                o_acc[1] = __builtin_amdgcn_mfma_f32_16x16x32_bf16(ap, fb, o_acc[1], 0, 0, 0);
            }
            {
                u32x4 vv = {r4.x, r4.y, r5.x, r5.y};
                bf16x8 fb; __builtin_memcpy(&fb, &vv, 16);
                o_acc[2] = __builtin_amdgcn_mfma_f32_16x16x32_bf16(ap, fb, o_acc[2], 0, 0, 0);
            }
            {
                u32x4 vv = {r6.x, r6.y, r7.x, r7.y};
                bf16x8 fb; __builtin_memcpy(&fb, &vv, 16);
                o_acc[3] = __builtin_amdgcn_mfma_f32_16x16x32_bf16(ap, fb, o_acc[3], 0, 0, 0);
            }
            __builtin_amdgcn_s_setprio(0);
        }
    }

#pragma unroll
    for (int j = 0; j < 4; ++j) {
        float lq = __shfl(l_i, fk8 * 4 + j);
        float inv = 1.f / lq;
        int grow = qt * 64 + wv * 16 + fk8 * 4 + j;
        size_t obase = ((size_t)(b * M_ + grow)) * DM_ + h * 64;
#pragma unroll
        for (int nf = 0; nf < 4; ++nf)
            O[obase + nf * 16 + frow] = f2bf(o_acc[nf][j] * inv);
    }
}

// ---------------------------------------------------------------------------
// LN over bf16 y with bf16 residual: out = LN(y + res + bias) * g + beta.
// MODE 0: emit bf16 (x1 path, in-place over res).  MODE 1: emit f32 (final).
// ---------------------------------------------------------------------------
template <int MODE>
__global__ __launch_bounds__(256) void ln_bf(const u16* __restrict__ y,
                                             const u16* __restrict__ resb,
                                             const float* __restrict__ bias,
                                             const float* __restrict__ g,
                                             const float* __restrict__ beta,
                                             float* __restrict__ outf,
                                             u16* __restrict__ outb) {
    __shared__ float red[2][4];
    const int row = blockIdx.x, tid = threadIdx.x;
    const size_t base = (size_t)row * 1024 + tid * 4;

    u32x2 yp = *reinterpret_cast<const u32x2*>(y + base);
    float v0 = bf2f((u16)(yp.x & 0xFFFF)), v1 = bf2f((u16)(yp.x >> 16));
    float v2 = bf2f((u16)(yp.y & 0xFFFF)), v3 = bf2f((u16)(yp.y >> 16));

    u32x2 rp = *reinterpret_cast<const u32x2*>(resb + base);
    float r0 = bf2f((u16)(rp.x & 0xFFFF)), r1 = bf2f((u16)(rp.x >> 16));
    float r2 = bf2f((u16)(rp.y & 0xFFFF)), r3 = bf2f((u16)(rp.y >> 16));

    float4 bb = *reinterpret_cast<const float4*>(bias + tid * 4);
    v0 += r0 + bb.x; v1 += r1 + bb.y; v2 += r2 + bb.z; v3 += r3 + bb.w;

    float sum = v0 + v1 + v2 + v3;
    float sq = v0 * v0 + v1 * v1 + v2 * v2 + v3 * v3;
#pragma unroll
    for (int off = 32; off; off >>= 1) {
        sum += __shfl_down(sum, off);
        sq += __shfl_down(sq, off);
    }
    if ((tid & 63) == 0) { red[0][tid >> 6] = sum; red[1][tid >> 6] = sq; }
    __syncthreads();
    sum = red[0][0] + red[0][1] + red[0][2] + red[0][3];
    sq = red[1][0] + red[1][1] + red[1][2] + red[1][3];
    float mu = sum * (1.f / 1024.f);
    float var = sq * (1.f / 1024.f) - mu * mu;
    float rstd = rsqrtf(var + 1e-12f);
    float4 gg = *reinterpret_cast<const float4*>(g + tid * 4);
    float4 be = *reinterpret_cast<const float4*>(beta + tid * 4);
    float o0 = (v0 - mu) * rstd * gg.x + be.x;
    float o1 = (v1 - mu) * rstd * gg.y + be.y;
    float o2 = (v2 - mu) * rstd * gg.z + be.z;
    float o3 = (v3 - mu) * rstd * gg.w + be.w;
    if (MODE == 1) {
        float4 o = {o0, o1, o2, o3};
        *reinterpret_cast<float4*>(outf + base) = o;
    } else {
        unsigned long long p = (unsigned long long)f2bf(o0)
                             | ((unsigned long long)f2bf(o1) << 16)
                             | ((unsigned long long)f2bf(o2) << 32)
                             | ((unsigned long long)f2bf(o3) << 48);
        *reinterpret_cast<unsigned long long*>(outb + base) = p;
    }
}

// ---------------------------------------------------------------------------
extern "C" void kernel_launch(void* const* d_in, const int* in_sizes, int n_in,
                              void* d_out, int out_size, void* d_ws, size_t ws_size,
                              hipStream_t stream) {
    const float* x    = (const float*)d_in[0];
    const float* mask = (const float*)d_in[1];
    const float* Pq   = (const float*)d_in[2];
    const float* Vq   = (const float*)d_in[3];
    const float* bq   = (const float*)d_in[4];
    const float* Pk   = (const float*)d_in[5];
    const float* Vk   = (const float*)d_in[6];
    const float* bk   = (const float*)d_in[7];
    const float* Pv   = (const float*)d_in[8];
    const float* Vv   = (const float*)d_in[9];
    const float* bv   = (const float*)d_in[10];
    const float* Uo   = (const float*)d_in[11];
    const float* Vo   = (const float*)d_in[12];
    const float* bo   = (const float*)d_in[13];
    const float* g1   = (const float*)d_in[14];
    const float* be1  = (const float*)d_in[15];
    const float* U1   = (const float*)d_in[16];
    const float* V1   = (const float*)d_in[17];
    const float* b1   = (const float*)d_in[18];
    const float* U2   = (const float*)d_in[19];
    const float* V2   = (const float*)d_in[20];
    const float* b2   = (const float*)d_in[21];
    const float* g2   = (const float*)d_in[22];
    const float* be2  = (const float*)d_in[23];
    float* out = (float*)d_out;

    const size_t MB = 1048576;
    char* ws = (char*)d_ws;
    u16* Pt  = (u16*)(ws + 0);                 // 3 MB (1536 x 1024 bf16)
    u16* Ftq = (u16*)(ws + 3 * MB);
    u16* Ftk = (u16*)(ws + 3 * MB + 131072);
    u16* Ftv = (u16*)(ws + 3 * MB + 262144);
    u16* Uob = (u16*)(ws + 4 * MB);            // 1 MB (1024 x 512, bf16 of Uo)
    u16* Vot = (u16*)(ws + 5 * MB);            // 1 MB (1024 x 512, Vo^T)
    u16* U1t = (u16*)(ws + 6 * MB);            // 1 MB (512 x 1024)
    u16* V1t = (u16*)(ws + 7 * MB);            // 4 MB (4096 x 512)
    u16* U2t = (u16*)(ws + 11 * MB);           // 4 MB (512 x 4096)
    u16* V2t = (u16*)(ws + 15 * MB);           // 1 MB (1024 x 512)
    u16* Xb  = (u16*)(ws + 16 * MB);           // 16 MB (x bf16; later x1 bf16)
    u16* Qb  = (u16*)(ws + 56 * MB);           // 16 MB
    u16* Kb  = (u16*)(ws + 72 * MB);           // 16 MB
    u16* Vb  = (u16*)(ws + 88 * MB);           // 16 MB
    u16* Ob  = (u16*)(ws + 104 * MB);          // 16 MB
    u16* Hb  = (u16*)(ws + 32 * MB);           // 64 MB (reuses Q/K/V area later)
    u16* Yb  = (u16*)(ws + 56 * MB);           // 16 MB bf16 y (reuses Qb)
    u16* Tb  = (u16*)(ws + 96 * MB);           // 8 MB (8192 x 512 bf16)
    u16* Wot = (u16*)(ws + 120 * MB);          // 2 MB (1024 x 1024 fused Wo^T)

    // --- all precompute in one launch ---
    prep_all<<<4016, 256, 0, stream>>>(x, Pq, Pk, Pv, Vq, Vk, Vv,
                                       Uo, Vo, U1, V1, U2, V2,
                                       Xb, Pt, Ftq, Ftk, Ftv,
                                       Uob, Vot, U1t, V1t, U2t, V2t);

    // --- fused attn-out weight: Wot[n][k] = sum_r Vo[r][n] * Uo[k][r] ---
    gemm_bf16<0, 4><<<dim3(8, 8), 256, 0, stream>>>(Vot, Uob, nullptr, Wot, 512, 1024);

    // --- QKV: one fused GEMM (stage-1 matmul + per-head rank-32 epilogue) ---
    gemm_qkv<<<dim3(12, 64), 256, 0, stream>>>(Xb, Pt, Ftq, Ftk, Ftv,
                                               bq, bk, bv, Qb, Kb, Vb);

    // --- attention ---
    attn_mfma<<<2048, 256, 0, stream>>>(Qb, Kb, Vb, mask, Ob);

    // --- attn out proj (fused low-rank -> dense) + LN1 ---
    gemm_bf16<0, 4><<<dim3(8, 64), 256, 0, stream>>>(Ob, Wot, nullptr, Yb, 1024, 1024);
    ln_bf<0><<<8192, 256, 0, stream>>>(Yb, Xb, bo, g1, be1, nullptr, Xb);

    // --- FFN + LN2 ---
    gemm_db<<<dim3(8, 64), 256, 0, stream>>>(Xb, U1t, Tb, 1024, 512);
    gemm_bf16<2, 4><<<dim3(32, 64), 256, 0, stream>>>(Tb, V1t, b1, Hb, 512, 4096);
    gemm_db<<<dim3(8, 64), 256, 0, stream>>>(Hb, U2t, Tb, 4096, 512);
    gemm_bf16<0, 4><<<dim3(8, 64), 256, 0, stream>>>(Tb, V2t, nullptr, Yb, 512, 1024);
    ln_bf<1><<<8192, 256, 0, stream>>>(Yb, Xb, b2, g2, be2, out, nullptr);
}

// Round 13
// 321.956 us; speedup vs baseline: 1.0631x; 1.0486x over previous
//
#include <hip/hip_runtime.h>
#include <hip/hip_bf16.h>
#include <math.h>

typedef unsigned short u16;
typedef unsigned int u32;
typedef __attribute__((ext_vector_type(8))) short bf16x8;
typedef __attribute__((ext_vector_type(4))) float f32x4;
typedef __attribute__((ext_vector_type(2))) unsigned int u32x2;
typedef __attribute__((ext_vector_type(4))) unsigned int u32x4;

#define B_ 8
#define M_ 1024
#define DM_ 1024
#define H_ 16
#define DH_ 64
#define NR_ 8192

__device__ __forceinline__ u16 f2bf(float f) {
    unsigned u = __float_as_uint(f);
    u += 0x7FFFu + ((u >> 16) & 1u);
    return (u16)(u >> 16);
}

__device__ __forceinline__ float bf2f(u16 v) {
    return __uint_as_float((u32)v << 16);
}

__device__ __forceinline__ void gload16(const void* g, void* l) {
    __builtin_amdgcn_global_load_lds(
        (const __attribute__((address_space(1))) void*)g,
        (__attribute__((address_space(3))) void*)l, 16, 0, 0);
}

__device__ __forceinline__ u32 lds_addr(const void* p) {
    return (u32)(uintptr_t)(const __attribute__((address_space(3))) void*)p;
}

// ---------------------------------------------------------------------------
// Mega-prep: x->bf16, P transposes, V-factor transposes, 6 weight transposes.
// ---------------------------------------------------------------------------
__device__ void conv_dev(const float* __restrict__ in, u16* __restrict__ out,
                         int bid, int tid) {
#pragma unroll
    for (int j = 0; j < 4; ++j) {
        int i = bid * 4096 + j * 1024 + tid * 4;
        float4 v = *reinterpret_cast<const float4*>(in + i);
        unsigned long long p = (unsigned long long)f2bf(v.x)
                             | ((unsigned long long)f2bf(v.y) << 16)
                             | ((unsigned long long)f2bf(v.z) << 32)
                             | ((unsigned long long)f2bf(v.w) << 48);
        *reinterpret_cast<unsigned long long*>(out + i) = p;
    }
}

__device__ void prep_p_dev(const float* __restrict__ P, u16* __restrict__ Pt,
                           int h, int kc, int tid, float* sm) {
    float (*Ps)[33] = (float(*)[33])sm;
#pragma unroll
    for (int i = 0; i < 16; ++i) {
        int e = tid + i * 256;
        int kk = e >> 5, r = e & 31;
        Ps[kk][r] = P[(size_t)h * 32768 + (size_t)(kc + kk) * 32 + r];
    }
    __syncthreads();
#pragma unroll
    for (int i = 0; i < 16; ++i) {
        int e = tid + i * 256;
        int r = e >> 7, k = e & 127;
        Pt[(size_t)(h * 32 + r) * 1024 + kc + k] = f2bf(Ps[k][r]);
    }
}

__device__ void prep_f_dev(const float* __restrict__ V, u16* __restrict__ Ft,
                           int h, int tid, float* sm) {
    float (*Vs)[65] = (float(*)[65])sm;
#pragma unroll
    for (int i = 0; i < 8; ++i) {
        int e = tid + i * 256;
        int r = e >> 6, c = e & 63;
        Vs[r][c] = V[(size_t)h * 2048 + r * 64 + c];
    }
    __syncthreads();
#pragma unroll
    for (int i = 0; i < 8; ++i) {
        int idx = tid + i * 256;
        int e = idx >> 5, r = idx & 31;
        Ft[(size_t)h * 2560 + e * 40 + r] = f2bf(Vs[r][e]);
    }
}

__device__ void transp_dev(const float* __restrict__ in, u16* __restrict__ out,
                           int R, int C, int bx, int by, int tid, float* sm) {
    float (*t)[65] = (float(*)[65])sm;
    const int rb = by * 64, cb = bx * 64;
#pragma unroll
    for (int i = 0; i < 16; ++i) {
        int e = tid + i * 256;
        int r = e >> 6, c = e & 63;
        t[r][c] = in[(size_t)(rb + r) * C + cb + c];
    }
    __syncthreads();
#pragma unroll
    for (int i = 0; i < 16; ++i) {
        int e = tid + i * 256;
        int r = e >> 6, c = e & 63;
        out[(size_t)(cb + r) * R + rb + c] = f2bf(t[c][r]);
    }
}

__global__ __launch_bounds__(256) void prep_all(
    const float* __restrict__ x,
    const float* __restrict__ Pq, const float* __restrict__ Pk, const float* __restrict__ Pv,
    const float* __restrict__ Vq, const float* __restrict__ Vk, const float* __restrict__ Vv,
    const float* __restrict__ Uo, const float* __restrict__ Vo,
    const float* __restrict__ U1, const float* __restrict__ V1,
    const float* __restrict__ U2, const float* __restrict__ V2,
    u16* __restrict__ Xb, u16* __restrict__ Pt,
    u16* __restrict__ Ftq, u16* __restrict__ Ftk, u16* __restrict__ Ftv,
    u16* __restrict__ Uot, u16* __restrict__ Vot,
    u16* __restrict__ U1t, u16* __restrict__ V1t,
    u16* __restrict__ U2t, u16* __restrict__ V2t) {
    __shared__ float smem[4224];
    const int bid = blockIdx.x, tid = threadIdx.x;
    if (bid < 2048) {
        conv_dev(x, Xb, bid, tid);
    } else if (bid < 2432) {
        int t = bid - 2048, which = t >> 7, tt = t & 127;
        const float* P = which == 0 ? Pq : (which == 1 ? Pk : Pv);
        prep_p_dev(P, Pt + (size_t)which * 524288, tt >> 3, (tt & 7) * 128, tid, smem);
    } else if (bid < 2480) {
        int t = bid - 2432, which = t >> 4;
        const float* V = which == 0 ? Vq : (which == 1 ? Vk : Vv);
        u16* F = which == 0 ? Ftq : (which == 1 ? Ftk : Ftv);
        prep_f_dev(V, F, t & 15, tid, smem);
    } else if (bid < 2608) {
        int t = bid - 2480;
        transp_dev(Uo, Uot, 1024, 512, t & 7, t >> 3, tid, smem);
    } else if (bid < 2736) {
        int t = bid - 2608;
        transp_dev(Vo, Vot, 512, 1024, t & 15, t >> 4, tid, smem);
    } else if (bid < 2864) {
        int t = bid - 2736;
        transp_dev(U1, U1t, 1024, 512, t & 7, t >> 3, tid, smem);
    } else if (bid < 3376) {
        int t = bid - 2864;
        transp_dev(V1, V1t, 512, 4096, t & 63, t >> 6, tid, smem);
    } else if (bid < 3888) {
        int t = bid - 3376;
        transp_dev(U2, U2t, 4096, 512, t & 7, t >> 3, tid, smem);
    } else {
        int t = bid - 3888;
        transp_dev(V2, V2t, 512, 1024, t & 15, t >> 4, tid, smem);
    }
}

// ---------------------------------------------------------------------------
// bf16 MFMA GEMM (single-buffer): C(8192 x N) = A(8192 x K) @ Bt(N x K)^T
// EPI: 0 bf16, 2 bias+gelu bf16.
// ---------------------------------------------------------------------------
template <int EPI, int NF>
__global__ __launch_bounds__(256) void gemm_bf16(const u16* __restrict__ A,
                                                 const u16* __restrict__ Bt,
                                                 const float* __restrict__ bias,
                                                 void* __restrict__ Cout,
                                                 int K, int N) {
    constexpr int BN = NF * 32;
    __shared__ u16 As[128 * 64];
    __shared__ u16 Bs[BN * 64];
    const int tid = threadIdx.x;
    const int lane = tid & 63, wv = tid >> 6;

    const int NX = gridDim.x;
    const int flat = blockIdx.x + blockIdx.y * NX;
    const int q = (NX * gridDim.y) >> 3;
    const int nid = (flat & 7) * q + (flat >> 3);
    const int row0 = (nid / NX) * 128, col0 = (nid % NX) * BN;

    const int frow = lane & 15, fk8 = lane >> 4;
    const int wm = (wv >> 1) * 64, wn = (wv & 1) * (BN / 2);

    f32x4 acc[4][NF];
    const f32x4 z4 = {0.f, 0.f, 0.f, 0.f};
#pragma unroll
    for (int i = 0; i < 4; ++i)
#pragma unroll
        for (int j = 0; j < NF; ++j) acc[i][j] = z4;

    for (int k0 = 0; k0 < K; k0 += 64) {
#pragma unroll
        for (int i = 0; i < 4; ++i) {
            int rr = (i * 4 + wv) * 8 + (lane >> 3);
            int cc = ((lane & 7) ^ (rr & 7)) * 8;
            gload16(A + (size_t)(row0 + rr) * K + k0 + cc,
                    (char*)As + (i * 4 + wv) * 1024);
        }
#pragma unroll
        for (int i = 0; i < NF; ++i) {
            int rr = (i * 4 + wv) * 8 + (lane >> 3);
            int cc = ((lane & 7) ^ (rr & 7)) * 8;
            gload16(Bt + (size_t)(col0 + rr) * K + k0 + cc,
                    (char*)Bs + (i * 4 + wv) * 1024);
        }
        asm volatile("s_waitcnt vmcnt(0)" ::: "memory");
        __syncthreads();
#pragma unroll
        for (int kf = 0; kf < 2; ++kf) {
            bf16x8 af[4], bfr[NF];
#pragma unroll
            for (int mf = 0; mf < 4; ++mf) {
                int r = wm + mf * 16 + frow;
                int c16 = (kf * 4 + fk8) ^ (r & 7);
                af[mf] = *reinterpret_cast<const bf16x8*>((char*)As + r * 128 + c16 * 16);
            }
#pragma unroll
            for (int nf = 0; nf < NF; ++nf) {
                int r = wn + nf * 16 + frow;
                int c16 = (kf * 4 + fk8) ^ (r & 7);
                bfr[nf] = *reinterpret_cast<const bf16x8*>((char*)Bs + r * 128 + c16 * 16);
            }
#pragma unroll
            for (int mf = 0; mf < 4; ++mf)
#pragma unroll
                for (int nf = 0; nf < NF; ++nf)
                    acc[mf][nf] = __builtin_amdgcn_mfma_f32_16x16x32_bf16(
                        af[mf], bfr[nf], acc[mf][nf], 0, 0, 0);
        }
        __syncthreads();
    }

    const int orow = fk8 * 4, ocol = frow;
#pragma unroll
    for (int mf = 0; mf < 4; ++mf)
#pragma unroll
        for (int nf = 0; nf < NF; ++nf)
#pragma unroll
            for (int j = 0; j < 4; ++j) {
                int row = row0 + wm + mf * 16 + orow + j;
                int col = col0 + wn + nf * 16 + ocol;
                float v = acc[mf][nf][j];
                if (EPI == 2) {
                    v += bias[col];
                    v = 0.5f * v * (1.f + erff(v * 0.70710678118f));
                    ((u16*)Cout)[(size_t)row * N + col] = f2bf(v);
                } else {
                    ((u16*)Cout)[(size_t)row * N + col] = f2bf(v);
                }
            }
}

// ---------------------------------------------------------------------------
// QKV fused GEMM: stage-1 matmul kept in regs, per-head rank-32 transform in
// the epilogue via wave-local LDS transpose, direct Q/K/V (+bias) scatter.
// ---------------------------------------------------------------------------
__global__ __launch_bounds__(256) void gemm_qkv(const u16* __restrict__ A,
                                                const u16* __restrict__ Bt,
                                                const u16* __restrict__ Ftq,
                                                const u16* __restrict__ Ftk,
                                                const u16* __restrict__ Ftv,
                                                const float* __restrict__ bq,
                                                const float* __restrict__ bk,
                                                const float* __restrict__ bv,
                                                u16* __restrict__ Qo,
                                                u16* __restrict__ Ko,
                                                u16* __restrict__ Vo) {
    const int K = 1024;
    __shared__ u16 As[128 * 64];
    __shared__ u16 Bs[128 * 64];
    const int tid = threadIdx.x;
    const int lane = tid & 63, wv = tid >> 6;

    const int NX = gridDim.x;
    const int flat = blockIdx.x + blockIdx.y * NX;
    const int q = (NX * gridDim.y) >> 3;
    const int nid = (flat & 7) * q + (flat >> 3);
    const int row0 = (nid / NX) * 128, col0 = (nid % NX) * 128;

    const int frow = lane & 15, fk8 = lane >> 4;
    const int wm = (wv >> 1) * 64, wn = (wv & 1) * 64;

    f32x4 acc[4][4];
    const f32x4 z4 = {0.f, 0.f, 0.f, 0.f};
#pragma unroll
    for (int i = 0; i < 4; ++i)
#pragma unroll
        for (int j = 0; j < 4; ++j) acc[i][j] = z4;

    for (int k0 = 0; k0 < K; k0 += 64) {
#pragma unroll
        for (int i = 0; i < 4; ++i) {
            int rr = (i * 4 + wv) * 8 + (lane >> 3);
            int cc = ((lane & 7) ^ (rr & 7)) * 8;
            gload16(A + (size_t)(row0 + rr) * K + k0 + cc,
                    (char*)As + (i * 4 + wv) * 1024);
            gload16(Bt + (size_t)(col0 + rr) * K + k0 + cc,
                    (char*)Bs + (i * 4 + wv) * 1024);
        }
        asm volatile("s_waitcnt vmcnt(0)" ::: "memory");
        __syncthreads();
#pragma unroll
        for (int kf = 0; kf < 2; ++kf) {
            bf16x8 af[4], bfr[4];
#pragma unroll
            for (int mf = 0; mf < 4; ++mf) {
                int r = wm + mf * 16 + frow;
                int c16 = (kf * 4 + fk8) ^ (r & 7);
                af[mf] = *reinterpret_cast<const bf16x8*>((char*)As + r * 128 + c16 * 16);
            }
#pragma unroll
            for (int nf = 0; nf < 4; ++nf) {
                int r = wn + nf * 16 + frow;
                int c16 = (kf * 4 + fk8) ^ (r & 7);
                bfr[nf] = *reinterpret_cast<const bf16x8*>((char*)Bs + r * 128 + c16 * 16);
            }
#pragma unroll
            for (int mf = 0; mf < 4; ++mf)
#pragma unroll
                for (int nf = 0; nf < 4; ++nf)
                    acc[mf][nf] = __builtin_amdgcn_mfma_f32_16x16x32_bf16(
                        af[mf], bfr[nf], acc[mf][nf], 0, 0, 0);
        }
        __syncthreads();
    }

    // --- epilogue: per-head rank-32 transform -------------------------------
    u16* preg = (wv < 2) ? As + wv * 4096 : Bs + (wv - 2) * 4096;
#pragma unroll
    for (int mf = 0; mf < 4; ++mf)
#pragma unroll
        for (int nf = 0; nf < 4; ++nf)
#pragma unroll
            for (int j = 0; j < 4; ++j) {
                int r = mf * 16 + fk8 * 4 + j;
                int c = nf * 16 + frow;
                int byte = r * 128 + (((c >> 3) ^ (r & 7)) * 16) + (c & 7) * 2;
                *(u16*)((char*)preg + byte) = f2bf(acc[mf][nf][j]);
            }
    __syncthreads();

    const int f = col0 >> 9;                       // 0=q, 1=k, 2=v
    const u16* Ft = f == 0 ? Ftq : (f == 1 ? Ftk : Ftv);
    const float* bias = f == 0 ? bq : (f == 1 ? bk : bv);
    u16* outp = f == 0 ? Qo : (f == 1 ? Ko : Vo);
    const int h0 = (((col0 & 511) + wn) >> 5);

#pragma unroll
    for (int hh = 0; hh < 2; ++hh) {
        const int h = h0 + hh;
        const u16* ftb = Ft + (size_t)h * 2560;
        bf16x8 bf2[4];
#pragma unroll
        for (int ef = 0; ef < 4; ++ef) {
            int e = ef * 16 + frow;
            bf2[ef] = *reinterpret_cast<const bf16x8*>(ftb + e * 40 + fk8 * 8);
        }
#pragma unroll
        for (int mf = 0; mf < 4; ++mf) {
            int r = mf * 16 + frow;
            bf16x8 af = *reinterpret_cast<const bf16x8*>(
                (char*)preg + r * 128 + (((hh * 4 + fk8) ^ (r & 7)) * 16));
#pragma unroll
            for (int ef = 0; ef < 4; ++ef) {
                f32x4 o = __builtin_amdgcn_mfma_f32_16x16x32_bf16(af, bf2[ef], z4, 0, 0, 0);
                int e = ef * 16 + frow;
                float bv_ = bias[h * 64 + e];
#pragma unroll
                for (int j = 0; j < 4; ++j) {
                    int row = row0 + wm + mf * 16 + fk8 * 4 + j;
                    int bb = row >> 10, m = row & 1023;
                    outp[(((size_t)(bb * 16 + h) << 10) + m) * 64 + e] = f2bf(o[j] + bv_);
                }
            }
        }
    }
}

// ---------------------------------------------------------------------------
// Double-buffered prefetch GEMM for N=512 outputs (BN=64, bf16 out).
// ---------------------------------------------------------------------------
__global__ __launch_bounds__(256) void gemm_db(const u16* __restrict__ A,
                                               const u16* __restrict__ Bt,
                                               u16* __restrict__ Cout,
                                               int K, int N) {
    __shared__ u16 As[2][128 * 64];
    __shared__ u16 Bs[2][64 * 64];
    const int tid = threadIdx.x;
    const int lane = tid & 63, wv = tid >> 6;

    const int NX = gridDim.x;
    const int flat = blockIdx.x + blockIdx.y * NX;
    const int q = (NX * gridDim.y) >> 3;
    const int nid = (flat & 7) * q + (flat >> 3);
    const int row0 = (nid / NX) * 128, col0 = (nid % NX) * 64;

    const int frow = lane & 15, fk8 = lane >> 4;
    const int wm = (wv >> 1) * 64, wn = (wv & 1) * 32;

    f32x4 acc[4][2];
    const f32x4 z4 = {0.f, 0.f, 0.f, 0.f};
#pragma unroll
    for (int i = 0; i < 4; ++i) {
        acc[i][0] = z4;
        acc[i][1] = z4;
    }

    const int srr = (lane >> 3);
    const int scc = (lane & 7);

#pragma unroll
    for (int i = 0; i < 4; ++i) {
        int rr = (i * 4 + wv) * 8 + srr;
        int cc = (scc ^ (rr & 7)) * 8;
        gload16(A + (size_t)(row0 + rr) * K + cc, (char*)&As[0][0] + (i * 4 + wv) * 1024);
    }
#pragma unroll
    for (int i = 0; i < 2; ++i) {
        int rr = (i * 4 + wv) * 8 + srr;
        int cc = (scc ^ (rr & 7)) * 8;
        gload16(Bt + (size_t)(col0 + rr) * K + cc, (char*)&Bs[0][0] + (i * 4 + wv) * 1024);
    }

    int cur = 0;
    for (int k0 = 0; k0 < K; k0 += 64) {
        __syncthreads();
        if (k0 + 64 < K) {
            int kn = k0 + 64;
#pragma unroll
            for (int i = 0; i < 4; ++i) {
                int rr = (i * 4 + wv) * 8 + srr;
                int cc = (scc ^ (rr & 7)) * 8;
                gload16(A + (size_t)(row0 + rr) * K + kn + cc,
                        (char*)&As[cur ^ 1][0] + (i * 4 + wv) * 1024);
            }
#pragma unroll
            for (int i = 0; i < 2; ++i) {
                int rr = (i * 4 + wv) * 8 + srr;
                int cc = (scc ^ (rr & 7)) * 8;
                gload16(Bt + (size_t)(col0 + rr) * K + kn + cc,
                        (char*)&Bs[cur ^ 1][0] + (i * 4 + wv) * 1024);
            }
        }
#pragma unroll
        for (int kf = 0; kf < 2; ++kf) {
            bf16x8 af[4], bfr[2];
#pragma unroll
            for (int mf = 0; mf < 4; ++mf) {
                int r = wm + mf * 16 + frow;
                int c16 = (kf * 4 + fk8) ^ (r & 7);
                af[mf] = *reinterpret_cast<const bf16x8*>((char*)&As[cur][0] + r * 128 + c16 * 16);
            }
#pragma unroll
            for (int nf = 0; nf < 2; ++nf) {
                int r = wn + nf * 16 + frow;
                int c16 = (kf * 4 + fk8) ^ (r & 7);
                bfr[nf] = *reinterpret_cast<const bf16x8*>((char*)&Bs[cur][0] + r * 128 + c16 * 16);
            }
#pragma unroll
            for (int mf = 0; mf < 4; ++mf)
#pragma unroll
                for (int nf = 0; nf < 2; ++nf)
                    acc[mf][nf] = __builtin_amdgcn_mfma_f32_16x16x32_bf16(
                        af[mf], bfr[nf], acc[mf][nf], 0, 0, 0);
        }
        cur ^= 1;
    }

#pragma unroll
    for (int mf = 0; mf < 4; ++mf)
#pragma unroll
        for (int nf = 0; nf < 2; ++nf)
#pragma unroll
            for (int j = 0; j < 4; ++j) {
                int row = row0 + wm + mf * 16 + fk8 * 4 + j;
                int col = col0 + wn + nf * 16 + frow;
                Cout[(size_t)row * N + col] = f2bf(acc[mf][nf][j]);
            }
}

// ---------------------------------------------------------------------------
// MFMA flash attention — round-5 variant (best measured: 92 us).
// 256 threads, grid 2048 (XCD remap, qt innermost), single-buffered K/V,
// swapped QK^T, base-2 softmax + defer-max, XOR-swizzled P LDS,
// V subtiled [key/4][d/16][4][16] + ds_read_b64_tr_b16.
// ---------------------------------------------------------------------------
__global__ __launch_bounds__(256) void attn_mfma(const u16* __restrict__ Q,
                                                 const u16* __restrict__ K,
                                                 const u16* __restrict__ V,
                                                 const float* __restrict__ mask,
                                                 u16* __restrict__ O) {
    __shared__ u16 Ks[4096];
    __shared__ u16 Vt[4096];
    __shared__ u16 Pw[4096];
    const int flat = blockIdx.x;
    const int nid = (flat & 7) * 256 + (flat >> 3);
    const int hb = nid >> 4, qt = nid & 15;
    const int b = hb >> 4, h = hb & 15;
    const int tid = threadIdx.x, lane = tid & 63, wv = tid >> 6;
    const int frow = lane & 15, fk8 = lane >> 4;
    const size_t base = (size_t)hb * 65536;
    const float LOG2E = 1.44269504089f;
    const int srr = lane >> 3, scc = lane & 7;

#pragma unroll
    for (int i = 0; i < 2; ++i) {
        int rr = (i * 4 + wv) * 8 + srr;
        int cc = (scc ^ (rr & 7)) * 8;
        gload16(Q + base + (size_t)(qt * 64 + rr) * 64 + cc,
                (char*)Ks + (i * 4 + wv) * 1024);
    }
    asm volatile("s_waitcnt vmcnt(0)" ::: "memory");
    __syncthreads();
    bf16x8 qfrag[2];
#pragma unroll
    for (int kf = 0; kf < 2; ++kf) {
        int qr = wv * 16 + frow;
        int c16 = (kf * 4 + fk8) ^ (qr & 7);
        qfrag[kf] = *reinterpret_cast<const bf16x8*>((char*)Ks + qr * 128 + c16 * 16);
    }

    int voff[2];
#pragma unroll
    for (int i = 0; i < 2; ++i) {
        int c = (i * 4 + wv) * 64 + lane;
        int kb = c >> 5, db = (c >> 3) & 3, kr = (c >> 1) & 3, hf = c & 1;
        voff[i] = (kb * 4 + kr) * 64 + db * 16 + hf * 8;
    }

    u32 vta[4];
    {
        u32 vt0 = lds_addr(Vt) + fk8 * 1024 + frow * 2;
#pragma unroll
        for (int nf = 0; nf < 4; ++nf) vta[nf] = vt0 + nf * 128;
    }

    char* pwW = (char*)Pw + wv * 2048 + frow * 128 + (fk8 & 1) * 8;
    char* pwR = (char*)Pw + wv * 2048 + frow * 128;
    const float* mrow = mask + b * M_;

    float m_i = -1e30f, l_i = 0.f;
    const f32x4 z4 = {0.f, 0.f, 0.f, 0.f};
    f32x4 o_acc[4] = {z4, z4, z4, z4};

    for (int kt = 0; kt < 16; ++kt) {
        __syncthreads();
#pragma unroll
        for (int i = 0; i < 2; ++i) {
            int rr = (i * 4 + wv) * 8 + srr;
            int cc = (scc ^ (rr & 7)) * 8;
            gload16(K + base + (size_t)(kt * 64 + rr) * 64 + cc,
                    (char*)Ks + (i * 4 + wv) * 1024);
        }
#pragma unroll
        for (int i = 0; i < 2; ++i)
            gload16(V + base + kt * 4096 + voff[i], (char*)Vt + (i * 4 + wv) * 1024);
        asm volatile("s_waitcnt vmcnt(0)" ::: "memory");
        __syncthreads();

        f32x4 sacc[4] = {z4, z4, z4, z4};
        __builtin_amdgcn_s_setprio(1);
#pragma unroll
        for (int kf = 0; kf < 2; ++kf)
#pragma unroll
            for (int nf = 0; nf < 4; ++nf) {
                int kr = nf * 16 + frow;
                int c16 = (kf * 4 + fk8) ^ (kr & 7);
                bf16x8 ak = *reinterpret_cast<const bf16x8*>((char*)Ks + kr * 128 + c16 * 16);
                sacc[nf] = __builtin_amdgcn_mfma_f32_16x16x32_bf16(ak, qfrag[kf], sacc[nf], 0, 0, 0);
            }
        __builtin_amdgcn_s_setprio(0);

        float tval[4][4];
        float tmax = -1e30f;
#pragma unroll
        for (int nf = 0; nf < 4; ++nf) {
            float4 mk = *reinterpret_cast<const float4*>(mrow + kt * 64 + nf * 16 + fk8 * 4);
            float t0 = fmaf(sacc[nf][0], 0.125f, mk.x);
            float t1 = fmaf(sacc[nf][1], 0.125f, mk.y);
            float t2 = fmaf(sacc[nf][2], 0.125f, mk.z);
            float t3 = fmaf(sacc[nf][3], 0.125f, mk.w);
            tval[nf][0] = t0; tval[nf][1] = t1; tval[nf][2] = t2; tval[nf][3] = t3;
            tmax = fmaxf(tmax, fmaxf(fmaxf(t0, t1), fmaxf(t2, t3)));
        }
        tmax = fmaxf(tmax, __shfl_xor(tmax, 16));
        tmax = fmaxf(tmax, __shfl_xor(tmax, 32));

        if (__any(tmax > m_i + 8.f)) {
            float mnew = fmaxf(m_i, tmax);
            float c = exp2f((m_i - mnew) * LOG2E);
            m_i = mnew;
            l_i *= c;
#pragma unroll
            for (int j = 0; j < 4; ++j) {
                float cj = __shfl(c, fk8 * 4 + j);
#pragma unroll
                for (int nf = 0; nf < 4; ++nf) o_acc[nf][j] *= cj;
            }
        }

        const float ml = m_i * LOG2E;
        float rs = 0.f;
#pragma unroll
        for (int nf = 0; nf < 4; ++nf) {
            float p0 = exp2f(fmaf(tval[nf][0], LOG2E, -ml));
            float p1 = exp2f(fmaf(tval[nf][1], LOG2E, -ml));
            float p2 = exp2f(fmaf(tval[nf][2], LOG2E, -ml));
            float p3 = exp2f(fmaf(tval[nf][3], LOG2E, -ml));
            rs += (p0 + p1) + (p2 + p3);
            u32 w0 = __builtin_amdgcn_perm(__float_as_uint(p1), __float_as_uint(p0), 0x07060302u);
            u32 w1 = __builtin_amdgcn_perm(__float_as_uint(p3), __float_as_uint(p2), 0x07060302u);
            u32x2 wp = {w0, w1};
            *reinterpret_cast<u32x2*>(pwW + (((nf * 2 + (fk8 >> 1)) ^ (frow & 7)) * 16)) = wp;
        }
        rs += __shfl_xor(rs, 16);
        rs += __shfl_xor(rs, 32);
        l_i += rs;

#pragma unroll
        for (int kf = 0; kf < 2; ++kf) {
            bf16x8 ap = *reinterpret_cast<const bf16x8*>(pwR + (((kf * 4 + fk8) ^ (frow & 7)) * 16));
            u32x2 r0, r1, r2, r3, r4, r5, r6, r7;
            if (kf == 0) {
                asm volatile("ds_read_b64_tr_b16 %0, %1" : "=&v"(r0) : "v"(vta[0]));
                asm volatile("ds_read_b64_tr_b16 %0, %1 offset:512" : "=&v"(r1) : "v"(vta[0]));
                asm volatile("ds_read_b64_tr_b16 %0, %1" : "=&v"(r2) : "v"(vta[1]));
                asm volatile("ds_read_b64_tr_b16 %0, %1 offset:512" : "=&v"(r3) : "v"(vta[1]));
                asm volatile("ds_read_b64_tr_b16 %0, %1" : "=&v"(r4) : "v"(vta[2]));
                asm volatile("ds_read_b64_tr_b16 %0, %1 offset:512" : "=&v"(r5) : "v"(vta[2]));
                asm volatile("ds_read_b64_tr_b16 %0, %1" : "=&v"(r6) : "v"(vta[3]));
                asm volatile("ds_read_b64_tr_b16 %0, %1 offset:512" : "=&v"(r7) : "v"(vta[3]));
            } else {
                asm volatile("ds_read_b64_tr_b16 %0, %1 offset:4096" : "=&v"(r0) : "v"(vta[0]));
                asm volatile("ds_read_b64_tr_b16 %0, %1 offset:4608" : "=&v"(r1) : "v"(vta[0]));
                asm volatile("ds_read_b64_tr_b16 %0, %1 offset:4096" : "=&v"(r2) : "v"(vta[1]));
                asm volatile("ds_read_b64_tr_b16 %0, %1 offset:4608" : "=&v"(r3) : "v"(vta[1]));
                asm volatile("ds_read_b64_tr_b16 %0, %1 offset:4096" : "=&v"(r4) : "v"(vta[2]));
                asm volatile("ds_read_b64_tr_b16 %0, %1 offset:4608" : "=&v"(r5) : "v"(vta[2]));
                asm volatile("ds_read_b64_tr_b16 %0, %1 offset:4096" : "=&v"(r6) : "v"(vta[3]));
                asm volatile("ds_read_b64_tr_b16 %0, %1 offset:4608" : "=&v"(r7) : "v"(vta[3]));
            }
            asm volatile("s_waitcnt lgkmcnt(0)" ::: "memory");
            __builtin_amdgcn_sched_barrier(0);
            __builtin_amdgcn_s_setprio(1);
            {
                u32x4 vv = {r0.x, r0.y, r1.x, r1.y};
                bf16x8 fb; __builtin_memcpy(&fb, &vv, 16);
                o_acc[0] = __builtin_amdgcn_mfma_f32_16x16x32_bf16(ap, fb, o_acc[0], 0, 0, 0);
            }
            {
                u32x4 vv = {r2.x, r2.y, r3.x, r3.y};
                bf16x8 fb; __builtin_memcpy(&fb, &vv, 16);
                o_acc[1] = __builtin_amdgcn_mfma_f32_16x16x32_bf16(ap, fb, o_acc[1], 0, 0, 0);
            }
            {
                u32x4 vv = {r4.x, r4.y, r5.x, r5.y};
                bf16x8 fb; __builtin_memcpy(&fb, &vv, 16);
                o_acc[2] = __builtin_amdgcn_mfma_f32_16x16x32_bf16(ap, fb, o_acc[2], 0, 0, 0);
            }
            {
                u32x4 vv = {r6.x, r6.y, r7.x, r7.y};
                bf16x8 fb; __builtin_memcpy(&fb, &vv, 16);
                o_acc[3] = __builtin_amdgcn_mfma_f32_16x16x32_bf16(ap, fb, o_acc[3], 0, 0, 0);
            }
            __builtin_amdgcn_s_setprio(0);
        }
    }

#pragma unroll
    for (int j = 0; j < 4; ++j) {
        float lq = __shfl(l_i, fk8 * 4 + j);
        float inv = 1.f / lq;
        int grow = qt * 64 + wv * 16 + fk8 * 4 + j;
        size_t obase = ((size_t)(b * M_ + grow)) * DM_ + h * 64;
#pragma unroll
        for (int nf = 0; nf < 4; ++nf)
            O[obase + nf * 16 + frow] = f2bf(o_acc[nf][j] * inv);
    }
}

// ---------------------------------------------------------------------------
// LN over bf16 y with bf16 residual: out = LN(y + res + bias) * g + beta.
// MODE 0: emit bf16 (x1 path, in-place over res).  MODE 1: emit f32 (final).
// ---------------------------------------------------------------------------
template <int MODE>
__global__ __launch_bounds__(256) void ln_bf(const u16* __restrict__ y,
                                             const u16* __restrict__ resb,
                                             const float* __restrict__ bias,
                                             const float* __restrict__ g,
                                             const float* __restrict__ beta,
                                             float* __restrict__ outf,
                                             u16* __restrict__ outb) {
    __shared__ float red[2][4];
    const int row = blockIdx.x, tid = threadIdx.x;
    const size_t base = (size_t)row * 1024 + tid * 4;

    u32x2 yp = *reinterpret_cast<const u32x2*>(y + base);
    float v0 = bf2f((u16)(yp.x & 0xFFFF)), v1 = bf2f((u16)(yp.x >> 16));
    float v2 = bf2f((u16)(yp.y & 0xFFFF)), v3 = bf2f((u16)(yp.y >> 16));

    u32x2 rp = *reinterpret_cast<const u32x2*>(resb + base);
    float r0 = bf2f((u16)(rp.x & 0xFFFF)), r1 = bf2f((u16)(rp.x >> 16));
    float r2 = bf2f((u16)(rp.y & 0xFFFF)), r3 = bf2f((u16)(rp.y >> 16));

    float4 bb = *reinterpret_cast<const float4*>(bias + tid * 4);
    v0 += r0 + bb.x; v1 += r1 + bb.y; v2 += r2 + bb.z; v3 += r3 + bb.w;

    float sum = v0 + v1 + v2 + v3;
    float sq = v0 * v0 + v1 * v1 + v2 * v2 + v3 * v3;
#pragma unroll
    for (int off = 32; off; off >>= 1) {
        sum += __shfl_down(sum, off);
        sq += __shfl_down(sq, off);
    }
    if ((tid & 63) == 0) { red[0][tid >> 6] = sum; red[1][tid >> 6] = sq; }
    __syncthreads();
    sum = red[0][0] + red[0][1] + red[0][2] + red[0][3];
    sq = red[1][0] + red[1][1] + red[1][2] + red[1][3];
    float mu = sum * (1.f / 1024.f);
    float var = sq * (1.f / 1024.f) - mu * mu;
    float rstd = rsqrtf(var + 1e-12f);
    float4 gg = *reinterpret_cast<const float4*>(g + tid * 4);
    float4 be = *reinterpret_cast<const float4*>(beta + tid * 4);
    float o0 = (v0 - mu) * rstd * gg.x + be.x;
    float o1 = (v1 - mu) * rstd * gg.y + be.y;
    float o2 = (v2 - mu) * rstd * gg.z + be.z;
    float o3 = (v3 - mu) * rstd * gg.w + be.w;
    if (MODE == 1) {
        float4 o = {o0, o1, o2, o3};
        *reinterpret_cast<float4*>(outf + base) = o;
    } else {
        unsigned long long p = (unsigned long long)f2bf(o0)
                             | ((unsigned long long)f2bf(o1) << 16)
                             | ((unsigned long long)f2bf(o2) << 32)
                             | ((unsigned long long)f2bf(o3) << 48);
        *reinterpret_cast<unsigned long long*>(outb + base) = p;
    }
}

// ---------------------------------------------------------------------------
extern "C" void kernel_launch(void* const* d_in, const int* in_sizes, int n_in,
                              void* d_out, int out_size, void* d_ws, size_t ws_size,
                              hipStream_t stream) {
    const float* x    = (const float*)d_in[0];
    const float* mask = (const float*)d_in[1];
    const float* Pq   = (const float*)d_in[2];
    const float* Vq   = (const float*)d_in[3];
    const float* bq   = (const float*)d_in[4];
    const float* Pk   = (const float*)d_in[5];
    const float* Vk   = (const float*)d_in[6];
    const float* bk   = (const float*)d_in[7];
    const float* Pv   = (const float*)d_in[8];
    const float* Vv   = (const float*)d_in[9];
    const float* bv   = (const float*)d_in[10];
    const float* Uo   = (const float*)d_in[11];
    const float* Vo   = (const float*)d_in[12];
    const float* bo   = (const float*)d_in[13];
    const float* g1   = (const float*)d_in[14];
    const float* be1  = (const float*)d_in[15];
    const float* U1   = (const float*)d_in[16];
    const float* V1   = (const float*)d_in[17];
    const float* b1   = (const float*)d_in[18];
    const float* U2   = (const float*)d_in[19];
    const float* V2   = (const float*)d_in[20];
    const float* b2   = (const float*)d_in[21];
    const float* g2   = (const float*)d_in[22];
    const float* be2  = (const float*)d_in[23];
    float* out = (float*)d_out;

    const size_t MB = 1048576;
    char* ws = (char*)d_ws;
    u16* Pt  = (u16*)(ws + 0);                 // 3 MB (1536 x 1024 bf16)
    u16* Ftq = (u16*)(ws + 3 * MB);
    u16* Ftk = (u16*)(ws + 3 * MB + 131072);
    u16* Ftv = (u16*)(ws + 3 * MB + 262144);
    u16* Uot = (u16*)(ws + 4 * MB);            // 1 MB (512 x 1024)
    u16* Vot = (u16*)(ws + 5 * MB);            // 1 MB (1024 x 512)
    u16* U1t = (u16*)(ws + 6 * MB);            // 1 MB (512 x 1024)
    u16* V1t = (u16*)(ws + 7 * MB);            // 4 MB (4096 x 512)
    u16* U2t = (u16*)(ws + 11 * MB);           // 4 MB (512 x 4096)
    u16* V2t = (u16*)(ws + 15 * MB);           // 1 MB (1024 x 512)
    u16* Xb  = (u16*)(ws + 16 * MB);           // 16 MB (x bf16; later x1 bf16)
    u16* Qb  = (u16*)(ws + 56 * MB);           // 16 MB
    u16* Kb  = (u16*)(ws + 72 * MB);           // 16 MB
    u16* Vb  = (u16*)(ws + 88 * MB);           // 16 MB
    u16* Ob  = (u16*)(ws + 104 * MB);          // 16 MB
    u16* Hb  = (u16*)(ws + 32 * MB);           // 64 MB (reuses Q/K/V area later)
    u16* Yb  = (u16*)(ws + 56 * MB);           // 16 MB bf16 y (reuses Qb)
    u16* Tb  = (u16*)(ws + 96 * MB);           // 8 MB (8192 x 512 bf16)

    // --- all precompute in one launch ---
    prep_all<<<4016, 256, 0, stream>>>(x, Pq, Pk, Pv, Vq, Vk, Vv,
                                       Uo, Vo, U1, V1, U2, V2,
                                       Xb, Pt, Ftq, Ftk, Ftv,
                                       Uot, Vot, U1t, V1t, U2t, V2t);

    // --- QKV: one fused GEMM (stage-1 matmul + per-head rank-32 epilogue) ---
    gemm_qkv<<<dim3(12, 64), 256, 0, stream>>>(Xb, Pt, Ftq, Ftk, Ftv,
                                               bq, bk, bv, Qb, Kb, Vb);

    // --- attention (round-5 best-measured variant) ---
    attn_mfma<<<2048, 256, 0, stream>>>(Qb, Kb, Vb, mask, Ob);

    // --- attn out proj + LN1 (bf16 y, bf16 residual from Xb) ---
    gemm_db<<<dim3(8, 64), 256, 0, stream>>>(Ob, Uot, Tb, 1024, 512);
    gemm_bf16<0, 4><<<dim3(8, 64), 256, 0, stream>>>(Tb, Vot, nullptr, Yb, 512, 1024);
    ln_bf<0><<<8192, 256, 0, stream>>>(Yb, Xb, bo, g1, be1, nullptr, Xb);

    // --- FFN + LN2 (bf16 y + bf16 residual) ---
    gemm_db<<<dim3(8, 64), 256, 0, stream>>>(Xb, U1t, Tb, 1024, 512);
    gemm_bf16<2, 4><<<dim3(32, 64), 256, 0, stream>>>(Tb, V1t, b1, Hb, 512, 4096);
    gemm_db<<<dim3(8, 64), 256, 0, stream>>>(Hb, U2t, Tb, 4096, 512);
    gemm_bf16<0, 4><<<dim3(8, 64), 256, 0, stream>>>(Tb, V2t, nullptr, Yb, 512, 1024);
    ln_bf<1><<<8192, 256, 0, stream>>>(Yb, Xb, b2, g2, be2, out, nullptr);
}